// Round 11
// baseline (628.288 us; speedup 1.0000x reference)
//
#include <hip/hip_runtime.h>
#include <hip/hip_cooperative_groups.h>
#include <math.h>

namespace cg = cooperative_groups;

#define HP 258
#define RPAD 320
#define BSTR 328              // bf16 row stride (656B, 16B-aligned)
#define NPIX (HP*HP)
#define NPB  (RPAD*BSTR)
#define PTOT (RPAD*BSTR)
#define C30 30
#define TOT (C30*NPIX)
#define LOGW 64
#define PBLK 410              // ceil(PTOT/256)
#define CH 3

typedef __bf16 bf16x8 __attribute__((ext_vector_type(8)));
typedef float  f32x4  __attribute__((ext_vector_type(4)));
typedef unsigned short ushort;
typedef unsigned short ushort8 __attribute__((ext_vector_type(8)));

static __device__ inline ushort f2bf(float f){
  __bf16 h = (__bf16)f;
  return __builtin_bit_cast(ushort, h);
}
static __device__ inline float bf2f(ushort u){
  return (float)__builtin_bit_cast(__bf16, u);
}

#define SM_BYTES 37568

#define MM_MFMA_HALF(KK)                                                       \
  {                                                                            \
    bf16x8 a0 = __builtin_bit_cast(bf16x8, *(const ushort8*)(&As[(wr      + l15)*72 + (KK) + lq*8])); \
    bf16x8 a1 = __builtin_bit_cast(bf16x8, *(const ushort8*)(&As[(wr + 16 + l15)*72 + (KK) + lq*8])); \
    bf16x8 b0 = __builtin_bit_cast(bf16x8, *(const ushort8*)(&Bs[(wc      + l15)*72 + (KK) + lq*8])); \
    bf16x8 b1 = __builtin_bit_cast(bf16x8, *(const ushort8*)(&Bs[(wc + 16 + l15)*72 + (KK) + lq*8])); \
    acc00 = __builtin_amdgcn_mfma_f32_16x16x32_bf16(a0, b0, acc00, 0, 0, 0);   \
    acc01 = __builtin_amdgcn_mfma_f32_16x16x32_bf16(a0, b1, acc01, 0, 0, 0);   \
    acc10 = __builtin_amdgcn_mfma_f32_16x16x32_bf16(a1, b0, acc10, 0, 0, 0);   \
    acc11 = __builtin_amdgcn_mfma_f32_16x16x32_bf16(a1, b1, acc11, 0, 0, 0);   \
  }

// ---------------- shared device bodies (used by mega AND fallback) ----------
static __device__ inline void mm_store_body(const ushort* __restrict__ Ab0,
                                            const ushort* __restrict__ Bb0,
                                            float* __restrict__ Cb,
                                            int bx, int by, int tid,
                                            ushort* As, ushort* Bs){
  int lane = tid & 63, wv = tid >> 6;
  int wr = (wv >> 1)*32, wc = (wv & 1)*32;
  int rowBase = bx*64, colBase = by*64;
  int l15 = lane & 15, lq = lane >> 4;
  f32x4 acc00 = {0.f,0.f,0.f,0.f}, acc01 = acc00, acc10 = acc00, acc11 = acc00;
  int srow = tid >> 3, sc8 = tid & 7;
  const ushort* Ab = Ab0 + (size_t)rowBase*BSTR;
  const ushort* Bb = Bb0 + (size_t)colBase*BSTR;
  const ushort* apt = Ab + (size_t)srow*BSTR + sc8*8;
  const ushort* bpt = Bb + (size_t)srow*BSTR + sc8*8;
  for (int k0 = 0; k0 < 256; k0 += 64){
    *(ushort8*)(&As[srow*72 + sc8*8])      = *(const ushort8*)(apt + k0);
    *(ushort8*)(&As[(srow+32)*72 + sc8*8]) = *(const ushort8*)(apt + (size_t)32*BSTR + k0);
    *(ushort8*)(&Bs[srow*72 + sc8*8])      = *(const ushort8*)(bpt + k0);
    *(ushort8*)(&Bs[(srow+32)*72 + sc8*8]) = *(const ushort8*)(bpt + (size_t)32*BSTR + k0);
    __syncthreads();
    MM_MFMA_HALF(0);
    MM_MFMA_HALF(32);
    __syncthreads();
  }
  {
    int row4 = tid >> 2, c84 = tid & 3;
    *(ushort8*)(&As[row4*72 + c84*8]) = *(const ushort8*)(Ab + (size_t)row4*BSTR + 256 + c84*8);
    *(ushort8*)(&Bs[row4*72 + c84*8]) = *(const ushort8*)(Bb + (size_t)row4*BSTR + 256 + c84*8);
    __syncthreads();
    MM_MFMA_HALF(0);
  }
  auto store = [&](f32x4 v, int r0, int c0){
    if (c0 < HP){
      #pragma unroll
      for (int r=0;r<4;r++){
        int rr = r0 + r;
        if (rr < HP) Cb[(size_t)rr*HP + c0] = v[r];
      }
    }
  };
  store(acc00, rowBase + wr +      lq*4, colBase + wc +      l15);
  store(acc01, rowBase + wr +      lq*4, colBase + wc + 16 + l15);
  store(acc10, rowBase + wr + 16 + lq*4, colBase + wc +      l15);
  store(acc11, rowBase + wr + 16 + lq*4, colBase + wc + 16 + l15);
}

static __device__ inline void mm_abs_body(bool negb,
                                          const ushort* __restrict__ Ab0,
                                          const ushort* __restrict__ Bb0,
                                          const float* __restrict__ Ob,
                                          double* __restrict__ partslot,
                                          int bx, int by, int tid,
                                          ushort* As, ushort* Bs, double* red){
  int lane = tid & 63, wv = tid >> 6;
  int wr = (wv >> 1)*32, wc = (wv & 1)*32;
  int rowBase = bx*64, colBase = by*64;
  int l15 = lane & 15, lq = lane >> 4;
  f32x4 acc00 = {0.f,0.f,0.f,0.f}, acc01 = acc00, acc10 = acc00, acc11 = acc00;
  int srow = tid >> 3, sc8 = tid & 7;
  const ushort* Ab = Ab0 + (size_t)rowBase*BSTR;
  const ushort* Bb = Bb0 + (size_t)colBase*BSTR;
  const ushort* apt = Ab + (size_t)srow*BSTR + sc8*8;
  const ushort* bpt = Bb + (size_t)srow*BSTR + sc8*8;
  ushort one = f2bf(1.0f);
  auto fixB = [&](ushort8 t8, int brow, int kbase)->ushort8{
    if (!negb) return t8;
    if (brow >= HP) return t8;
    #pragma unroll
    for (int i=0;i<8;i++){
      int kk = kbase + i;
      if (kk < HP)
        t8[i] = (brow==0 || brow==HP-1 || kk==0 || kk==HP-1) ? one : (ushort)(t8[i] ^ 0x8000);
    }
    return t8;
  };
  for (int k0 = 0; k0 < 256; k0 += 64){
    *(ushort8*)(&As[srow*72 + sc8*8])      = *(const ushort8*)(apt + k0);
    *(ushort8*)(&As[(srow+32)*72 + sc8*8]) = *(const ushort8*)(apt + (size_t)32*BSTR + k0);
    *(ushort8*)(&Bs[srow*72 + sc8*8])      = fixB(*(const ushort8*)(bpt + k0), colBase + srow, k0 + sc8*8);
    *(ushort8*)(&Bs[(srow+32)*72 + sc8*8]) = fixB(*(const ushort8*)(bpt + (size_t)32*BSTR + k0), colBase + srow + 32, k0 + sc8*8);
    __syncthreads();
    MM_MFMA_HALF(0);
    MM_MFMA_HALF(32);
    __syncthreads();
  }
  {
    int row4 = tid >> 2, c84 = tid & 3;
    *(ushort8*)(&As[row4*72 + c84*8]) = *(const ushort8*)(Ab + (size_t)row4*BSTR + 256 + c84*8);
    *(ushort8*)(&Bs[row4*72 + c84*8]) = fixB(*(const ushort8*)(Bb + (size_t)row4*BSTR + 256 + c84*8), colBase + row4, 256 + c84*8);
    __syncthreads();
    MM_MFMA_HALF(0);
  }
  double local = 0.0;
  auto addq = [&](f32x4 v, int r0, int c0){
    if (c0 < HP){
      #pragma unroll
      for (int r=0;r<4;r++){
        int rr = r0 + r;
        if (rr < HP){
          float o = Ob[(size_t)rr*HP + c0];
          if (negb) o = (rr==0||rr==HP-1||c0==0||c0==HP-1) ? 1.0f : -o;
          local += (double)fabsf(o - v[r]);
        }
      }
    }
  };
  addq(acc00, rowBase + wr +      lq*4, colBase + wc +      l15);
  addq(acc01, rowBase + wr +      lq*4, colBase + wc + 16 + l15);
  addq(acc10, rowBase + wr + 16 + lq*4, colBase + wc +      l15);
  addq(acc11, rowBase + wr + 16 + lq*4, colBase + wc + 16 + l15);
  red[tid] = local;
  __syncthreads();
  for (int s=128; s>0; s>>=1){ if (tid<s) red[tid]+=red[tid+s]; __syncthreads(); }
  if (tid==0) *partslot = red[0];
}

static __device__ inline void cm_body(int ch, const float* __restrict__ apart_,
                                      const float* __restrict__ xpart_,
                                      const float* __restrict__ XPd,
                                      float* __restrict__ cmo,
                                      float* colA, int tid){
  const float* ap = apart_ + (size_t)ch*10*320;
  for (int k = tid; k < HP; k += 256){
    float s = 0.0f;
    #pragma unroll
    for (int t=0;t<10;t++) s += ap[t*320 + k];
    colA[k] = s;
  }
  __syncthreads();
  const float* xpd = XPd + (size_t)ch*NPIX;
  const float* xp2 = xpart_ + (size_t)ch*10*320;
  for (int w = tid; w < HP; w += 256){
    float acc = 0.0f;
    for (int k=0;k<HP;k++) acc = fmaf(colA[k], xpd[(size_t)k*HP + w], acc);
    float xs = 0.0f;
    #pragma unroll
    for (int t=0;t<10;t++) xs += xp2[t*320 + w];
    cmo[ch*HP + w] = (acc - xs) * (1.0f/(float)HP);
  }
}

static __device__ inline void buildall_item(const float* __restrict__ logits,
    float* __restrict__ XP, ushort* __restrict__ BFT,
    ushort* __restrict__ BF1, ushort* __restrict__ BF2,
    float* __restrict__ xpart, float* __restrict__ apart,
    int tile, int chunk, int tid, char* SM){
  float (*s6)[34][35] = (float(*)[34][35])(SM);
  float (*fcb)[35]    = (float(*)[35])(SM + 28560);
  ushort (*tbuf)[33]  = (ushort(*)[33])(SM + 33320);
  float (*cr)[8][33]  = (float(*)[8][33])(SM + 35432);
  int tr = tile/10, tc = tile%10;
  int r0 = tr*32, c0 = tc*32;
  for (int idx = tid; idx < 34*34; idx += 256){
    int lr = idx/34, lc = idx%34;
    int h = r0 - 1 + lr, w = c0 - 1 + lc;
    float sv[6];
    if (h >= 1 && h <= 256 && w >= 1 && w <= 256){
      int oh = h-1, ow = w-1;
      float fy = 0.25f*oh - 0.375f;
      float fx = 0.25f*ow - 0.375f;
      float y0f = floorf(fy), x0f = floorf(fx);
      float ty = fy - y0f, tx2 = fx - x0f;
      int y0 = max(0, (int)y0f), y1 = min(LOGW-1, (int)y0f + 1);
      int x0 = max(0, (int)x0f), x1 = min(LOGW-1, (int)x0f + 1);
      float m = -3.402823466e+38f;
      #pragma unroll
      for (int c=0;c<6;c++){
        const float* pl = logits + c*LOGW*LOGW;
        float v00 = pl[y0*LOGW + x0], v01 = pl[y0*LOGW + x1];
        float v10 = pl[y1*LOGW + x0], v11 = pl[y1*LOGW + x1];
        float a = v00 + (v01 - v00)*tx2;
        float b = v10 + (v11 - v10)*tx2;
        float v = a + (b - a)*ty;
        sv[c] = v; m = fmaxf(m, v);
      }
      float sum = 0.0f;
      #pragma unroll
      for (int c=0;c<6;c++){ sv[c] = expf(sv[c]-m); sum += sv[c]; }
      float inv = 1.0f/sum;
      #pragma unroll
      for (int c=0;c<6;c++) sv[c] *= inv;
    } else {
      #pragma unroll
      for (int c=0;c<6;c++) sv[c] = 0.0f;
    }
    #pragma unroll
    for (int c=0;c<6;c++) s6[c][lr][lc] = sv[c];
  }
  __syncthreads();
  int tx = tid & 31, rg = tid >> 5;
  for (int cc=0; cc<CH; cc++){
    int ci = chunk*CH + cc;
    int i = ci/5, r = ci%5;
    int j = r + (r>=i ? 1 : 0);
    for (int idx = tid; idx < 34*34; idx += 256){
      int lr = idx/34, lc = idx%34;
      int h = r0 - 1 + lr, w = c0 - 1 + lc;
      float v;
      if (h < 0 || h >= HP || w < 0 || w >= HP) v = 0.0f;
      else if (h==0 || h==HP-1 || w==0 || w==HP-1) v = 1.0f;
      else v = fmaxf(0.5f*(s6[i][lr][lc] - s6[j][lr][lc]), 0.0f);
      fcb[lr][lc] = v;
    }
    __syncthreads();
    float xs_acc = 0.0f, as_acc = 0.0f;
    #pragma unroll
    for (int kk=0; kk<4; kk++){
      int lrow = rg + 8*kk;
      int h = r0 + lrow, w = c0 + tx;
      int lr = lrow + 1, lc = tx + 1;
      float xpv = fcb[lr][lc];
      ushort pmaxv, pavgv, xbfv;
      if (h >= HP || w >= HP){ pmaxv = 0; pavgv = 0; xbfv = 0; }
      else if (h==0 || h==HP-1 || w==0 || w==HP-1){
        pmaxv = f2bf(1.0f); pavgv = pmaxv; xbfv = pmaxv;
        XP[(size_t)ci*NPIX + (size_t)h*HP + w] = 1.0f;
        xs_acc += 1.0f;
        as_acc += 1.0f;
      } else {
        float mv = -3.402823466e+38f, av = 0.0f;
        #pragma unroll
        for (int dy=-1;dy<=1;dy++)
          #pragma unroll
          for (int dx=-1;dx<=1;dx++){
            float nv = fcb[lr+dy][lc+dx];
            mv = fmaxf(mv, nv); av += nv;
          }
        pmaxv = f2bf(mv);
        pavgv = f2bf(av*(1.0f/9.0f));
        xbfv  = f2bf(xpv);
        XP[(size_t)ci*NPIX + (size_t)h*HP + w] = xpv;
        xs_acc += xpv;
        as_acc += bf2f(pavgv);
      }
      size_t ob = (size_t)ci*NPB + (size_t)h*BSTR + w;
      BF1[ob] = pmaxv;
      BF2[ob] = pavgv;
      tbuf[lrow][tx] = xbfv;
    }
    cr[0][rg][tx] = xs_acc;
    cr[1][rg][tx] = as_acc;
    __syncthreads();
    if (tid < 32){
      float xs = 0.0f, as = 0.0f;
      #pragma unroll
      for (int g=0; g<8; g++){ xs += cr[0][g][tid]; as += cr[1][g][tid]; }
      xpart[((size_t)ci*10 + tr)*320 + c0 + tid] = xs;
      apart[((size_t)ci*10 + tr)*320 + c0 + tid] = as;
    }
    #pragma unroll
    for (int kk=0; kk<4; kk++){
      int a = rg + 8*kk;
      BFT[(size_t)ci*NPB + (size_t)(c0+a)*BSTR + (r0 + tx)] = tbuf[tx][a];
    }
    __syncthreads();
  }
}

static __device__ inline void poolrect_item(int ci, int sub, int tid,
    const float* __restrict__ F1, ushort* __restrict__ BF0,
    const float* __restrict__ XP, const float* __restrict__ F2,
    const float* __restrict__ cm, float* __restrict__ X1, ushort* __restrict__ BF2,
    float* __restrict__ x1part, float* __restrict__ a2part, char* SM){
  if (sub < PBLK){
    int p = sub*256 + tid;
    if (p < PTOT){
      int h = p / BSTR, w = p % BSTR;
      size_t ob = (size_t)ci*NPB + p;
      if (h >= HP || w >= HP) BF0[ob] = 0;
      else if (h==0 || h==HP-1 || w==0 || w==HP-1) BF0[ob] = f2bf(1.0f);
      else {
        const float* s = F1 + (size_t)ci*NPIX;
        float mv = -3.402823466e+38f;
        #pragma unroll
        for (int dy=-1;dy<=1;dy++){
          const float* rr = s + (size_t)(h+dy)*HP + (w-1);
          mv = fmaxf(mv, fmaxf(fmaxf(rr[0],rr[1]),rr[2]));
        }
        BF0[ob] = f2bf(mv);
      }
    }
    return;
  }
  float (*rect)[35] = (float(*)[35])(SM);
  float (*cr2)[8][33] = (float(*)[8][33])(SM + 4760);
  __syncthreads();
  int tl = sub - PBLK;
  int tcx = tl/10, tty = tl%10;
  int c0 = tcx*32, r0 = tty*32;
  const float* xb = XP + (size_t)ci*NPIX;
  const float* yb = F2 + (size_t)ci*NPIX;
  for (int idx = tid; idx < 34*34; idx += 256){
    int lr = idx/34, lc = idx%34;
    int h = r0 - 1 + lr, w = c0 - 1 + lc;
    float v = 0.0f;
    if (h >= 0 && h < HP && w >= 0 && w < HP){
      float xv = xb[(size_t)h*HP + w];
      float off = yb[(size_t)h*HP + w] - xv - cm[ci*HP + w];
      v = xv + fmaxf(off, 0.0f);
    }
    rect[lr][lc] = v;
  }
  __syncthreads();
  int tx = tid & 31, rg = tid >> 5;
  float xs_acc = 0.0f, as_acc = 0.0f;
  #pragma unroll
  for (int kk=0; kk<4; kk++){
    int lrow = rg + 8*kk;
    int h = r0 + lrow, w = c0 + tx;
    bool vpix = (h < HP && w < HP);
    ushort o;
    if (!vpix) o = 0;
    else {
      float xv = rect[lrow+1][tx+1];
      X1[(size_t)ci*NPIX + (size_t)h*HP + w] = xv;
      xs_acc += xv;
      if (h==0 || h==HP-1 || w==0 || w==HP-1){
        o = f2bf(1.0f);
        as_acc += 1.0f;
      } else {
        float av = (rect[lrow][tx]   + rect[lrow][tx+1]   + rect[lrow][tx+2])
                 + (rect[lrow+1][tx] + rect[lrow+1][tx+1] + rect[lrow+1][tx+2])
                 + (rect[lrow+2][tx] + rect[lrow+2][tx+1] + rect[lrow+2][tx+2]);
        o = f2bf(av*(1.0f/9.0f));
        as_acc += bf2f(o);
      }
    }
    if (h < RPAD && w < 320)
      BF2[(size_t)ci*NPB + (size_t)h*BSTR + w] = o;
  }
  cr2[0][rg][tx] = xs_acc;
  cr2[1][rg][tx] = as_acc;
  __syncthreads();
  if (tid < 32){
    float xs = 0.0f, as = 0.0f;
    #pragma unroll
    for (int g=0; g<8; g++){ xs += cr2[0][g][tid]; as += cr2[1][g][tid]; }
    x1part[((size_t)ci*10 + tty)*320 + c0 + tid] = xs;
    a2part[((size_t)ci*10 + tty)*320 + c0 + tid] = as;
  }
  __syncthreads();
}

static __device__ inline void invrect_item(int item, int tid,
    const float* __restrict__ F1, ushort* __restrict__ An,
    const float* __restrict__ X1, const float* __restrict__ F2,
    const float* __restrict__ cm, ushort* __restrict__ An2){
  bool second = (item >= PBLK);
  int p = (second ? item - PBLK : item)*256 + tid;
  if (p >= PTOT) return;
  int h = p / BSTR, w = p % BSTR;
  ushort* dst = second ? An2 : An;
  if (h >= HP || w >= HP){
    #pragma unroll
    for (int c=0;c<C30;c++) dst[(size_t)c*NPB+p] = 0;
    return;
  }
  int pd = h*HP + w;
  float v[C30];
  float ss = 0.0f;
  if (!second){
    #pragma unroll
    for (int c=0;c<C30;c++){ v[c] = F1[(size_t)c*NPIX+pd]; ss = fmaf(v[c],v[c],ss); }
  } else {
    #pragma unroll
    for (int c=0;c<C30;c++){
      float xv = X1[(size_t)c*NPIX + pd];
      float off = F2[(size_t)c*NPIX + pd] - xv - cm[c*HP + w];
      float vv = xv + fmaxf(off, 0.0f);
      v[c] = vv;
      ss = fmaf(vv, vv, ss);
    }
  }
  float n = sqrtf(2.0f*ss);
  float inv = 1.0f / fmaxf(n, 1e-12f);
  #pragma unroll
  for (int c=0;c<C30;c++) dst[(size_t)c*NPB+p] = f2bf(v[c]*inv);
}

// ================= mega kernel (cooperative) ================================
__global__ __launch_bounds__(256, 4) void mega_k(
    const float* __restrict__ logits, const float* __restrict__ base,
    float* __restrict__ out,
    float* __restrict__ XP, ushort* __restrict__ BFT,
    ushort* __restrict__ BF0, ushort* __restrict__ BF1, ushort* __restrict__ BF2,
    float* __restrict__ F1, float* __restrict__ F2, float* __restrict__ X1,
    float* __restrict__ cm, float* __restrict__ xpart, float* __restrict__ apart,
    float* __restrict__ x1part, float* __restrict__ a2part,
    double* __restrict__ part)
{
  cg::grid_group grid = cg::this_grid();
  __shared__ __align__(16) char SM[SM_BYTES];
  int tid = threadIdx.x;
  int gs = gridDim.x;

  for (int item = blockIdx.x; item < 1000; item += gs){
    __syncthreads();
    buildall_item(logits, XP, BFT, BF1, BF2, xpart, apart, item % 100, item / 100, tid, SM);
  }
  grid.sync();
  {
    ushort* As = (ushort*)SM;
    ushort* Bs = (ushort*)(SM + 9216);
    float*  colA = (float*)(SM + 18432);
    for (int item = blockIdx.x; item < 1530; item += gs){
      __syncthreads();
      if (item < 1500){
        int bx = item % 5, by = (item/5) % 5, z = item/25;
        bool dil = (z >= C30);
        int ch = dil ? z - C30 : z;
        mm_store_body((dil ? BF2 : BF1) + (size_t)ch*NPB, BFT + (size_t)ch*NPB,
                      (dil ? F2 : F1) + (size_t)ch*NPIX, bx, by, tid, As, Bs);
      } else {
        cm_body(item - 1500, apart, xpart, XP, cm, colA, tid);
      }
    }
  }
  grid.sync();
  for (int item = blockIdx.x; item < 30*510; item += gs){
    poolrect_item(item / 510, item % 510, tid, F1, BF0, XP, F2, cm, X1, BF2,
                  x1part, a2part, SM);
  }
  grid.sync();
  {
    ushort* As = (ushort*)SM;
    ushort* Bs = (ushort*)(SM + 9216);
    float*  colA = (float*)(SM + 18432);
    for (int item = blockIdx.x; item < 1530; item += gs){
      __syncthreads();
      if (item < 1500){
        int bx = item % 5, by = (item/5) % 5, z = item/25;
        bool dil = (z >= C30);
        int ch = dil ? z - C30 : z;
        mm_store_body((dil ? BF2 : BF0) + (size_t)ch*NPB, BFT + (size_t)ch*NPB,
                      (dil ? F2 : F1) + (size_t)ch*NPIX, bx, by, tid, As, Bs);
      } else {
        cm_body(item - 1500, a2part, x1part, XP, cm, colA, tid);
      }
    }
  }
  grid.sync();
  for (int item = blockIdx.x; item < 820; item += gs)
    invrect_item(item, tid, F1, BF1, X1, F2, cm, BF0);
  grid.sync();
  {
    ushort* As = (ushort*)SM;
    ushort* Bs = (ushort*)(SM + 9216);
    double* red = (double*)(SM + 18432);
    for (int item = blockIdx.x; item < 1500; item += gs){
      __syncthreads();
      int bx = item % 5, by = (item/5) % 5, z = item/25;
      bool negb = (z < C30);
      int ch = negb ? z : z - C30;
      mm_abs_body(negb, (negb ? BF1 : BF0) + (size_t)ch*NPB, BFT + (size_t)ch*NPB,
                  XP + (size_t)ch*NPIX, &part[(size_t)z*25 + by*5 + bx],
                  bx, by, tid, As, Bs, red);
    }
  }
  grid.sync();
  if (blockIdx.x == 0){
    double* s0 = (double*)SM;
    double* s1 = (double*)(SM + 2048);
    double l0 = 0.0, l1 = 0.0;
    for (int i=tid;i<750;i+=256){ l0 += part[i]; l1 += part[750+i]; }
    s0[tid]=l0; s1[tid]=l1; __syncthreads();
    for (int s=128;s>0;s>>=1){ if (tid<s){ s0[tid]+=s0[tid+s]; s1[tid]+=s1[tid+s]; } __syncthreads(); }
    if (tid==0) out[0] = (float)(fabs(2.0*(s0[0]-s1[0])) + (double)base[0]);
  }
}

// ================= fallback kernels (R9 path, verified) =====================
__global__ __launch_bounds__(256) void fb_buildall_k(const float* __restrict__ logits,
    float* __restrict__ XP, ushort* __restrict__ BFT,
    ushort* __restrict__ BF1, ushort* __restrict__ BF2,
    float* __restrict__ xpart, float* __restrict__ apart){
  __shared__ __align__(16) char SM[SM_BYTES];
  buildall_item(logits, XP, BFT, BF1, BF2, xpart, apart, blockIdx.x, blockIdx.y, threadIdx.x, SM);
}

__global__ __launch_bounds__(256) void fb_mm_k(const ushort* __restrict__ Aop,
    const ushort* __restrict__ Adil, const ushort* __restrict__ BT,
    float* __restrict__ Cop, float* __restrict__ Cdil,
    const float* __restrict__ XPd, const float* __restrict__ apart_,
    const float* __restrict__ xpart_, float* __restrict__ cmo){
  __shared__ __align__(16) char SM[20480];
  ushort* As = (ushort*)SM;
  ushort* Bs = (ushort*)(SM + 9216);
  float*  colA = (float*)(SM + 18432);
  int z = blockIdx.z;
  if (z >= 2*C30){
    int ch = (z - 2*C30)*25 + blockIdx.y*5 + blockIdx.x;
    if (ch >= C30) return;
    cm_body(ch, apart_, xpart_, XPd, cmo, colA, threadIdx.x);
    return;
  }
  bool dil = (z >= C30);
  int ch = dil ? z - C30 : z;
  mm_store_body((dil ? Adil : Aop) + (size_t)ch*NPB, BT + (size_t)ch*NPB,
                (dil ? Cdil : Cop) + (size_t)ch*NPIX,
                blockIdx.x, blockIdx.y, threadIdx.x, As, Bs);
}

__global__ __launch_bounds__(256) void fb_poolrect_k(const float* __restrict__ F1,
    ushort* __restrict__ BF0, const float* __restrict__ XP,
    const float* __restrict__ F2, const float* __restrict__ cm,
    float* __restrict__ X1, ushort* __restrict__ BF2,
    float* __restrict__ x1part, float* __restrict__ a2part){
  __shared__ __align__(16) char SM[7000];
  poolrect_item(blockIdx.y, blockIdx.x, threadIdx.x, F1, BF0, XP, F2, cm, X1, BF2,
                x1part, a2part, SM);
}

__global__ __launch_bounds__(256) void fb_invrect_k(const float* __restrict__ F1,
    ushort* __restrict__ An, const float* __restrict__ X1,
    const float* __restrict__ F2, const float* __restrict__ cm,
    ushort* __restrict__ An2){
  invrect_item(blockIdx.x, threadIdx.x, F1, An, X1, F2, cm, An2);
}

__global__ __launch_bounds__(256) void fb_mmabs_k(const ushort* __restrict__ Aop,
    const ushort* __restrict__ Adil, const ushort* __restrict__ BT,
    const float* __restrict__ XPop, double* __restrict__ part){
  __shared__ __align__(16) char SM[20480];
  ushort* As = (ushort*)SM;
  ushort* Bs = (ushort*)(SM + 9216);
  double* red = (double*)(SM + 18432);
  int z = blockIdx.z;
  bool negb = (z < C30);
  int ch = negb ? z : z - C30;
  mm_abs_body(negb, (negb ? Aop : Adil) + (size_t)ch*NPB, BT + (size_t)ch*NPB,
              XPop + (size_t)ch*NPIX, &part[(size_t)z*25 + blockIdx.y*5 + blockIdx.x],
              blockIdx.x, blockIdx.y, threadIdx.x, As, Bs, red);
}

__global__ void fb_finalize_k(const double* __restrict__ part,
                              const float* __restrict__ base, float* __restrict__ out){
  __shared__ double s0[256], s1[256];
  int tid = threadIdx.x;
  double l0=0.0, l1=0.0;
  for (int i=tid;i<750;i+=256){ l0 += part[i]; l1 += part[750+i]; }
  s0[tid]=l0; s1[tid]=l1; __syncthreads();
  for (int s=128;s>0;s>>=1){ if (tid<s){ s0[tid]+=s0[tid+s]; s1[tid]+=s1[tid+s]; } __syncthreads(); }
  if (tid==0) out[0] = (float)(fabs(2.0*(s0[0]-s1[0])) + (double)base[0]);
}

extern "C" void kernel_launch(void* const* d_in, const int* in_sizes, int n_in,
                              void* d_out, int out_size, void* d_ws, size_t ws_size,
                              hipStream_t stream){
  const float* logits = (const float*)d_in[0];
  const float* base   = (const float*)d_in[1];
  float* out = (float*)d_out;

  char* ws = (char*)d_ws;
  size_t off = 0;
  auto alloc = [&](size_t bytes)->char*{
    char* p = ws + off; off = (off + bytes + 255) & ~(size_t)255; return p;
  };
  double* part    = (double*)alloc(1500*sizeof(double));
  float*  cm      = (float*) alloc((size_t)C30*HP*sizeof(float));
  float*  xpart   = (float*) alloc((size_t)C30*10*320*sizeof(float));
  float*  apart   = (float*) alloc((size_t)C30*10*320*sizeof(float));
  float*  x1part  = (float*) alloc((size_t)C30*10*320*sizeof(float));
  float*  a2part  = (float*) alloc((size_t)C30*10*320*sizeof(float));
  float*  XP      = (float*) alloc((size_t)TOT*sizeof(float));
  ushort* BF0     = (ushort*)alloc((size_t)C30*NPB*sizeof(ushort));
  ushort* BFT     = (ushort*)alloc((size_t)C30*NPB*sizeof(ushort));
  ushort* BF1     = (ushort*)alloc((size_t)C30*NPB*sizeof(ushort));
  ushort* BF2     = (ushort*)alloc((size_t)C30*NPB*sizeof(ushort));
  float*  F1      = (float*) alloc((size_t)TOT*sizeof(float));
  float*  F2      = (float*) alloc((size_t)TOT*sizeof(float));
  float*  X1      = (float*) alloc((size_t)TOT*sizeof(float));
  (void)ws_size; (void)in_sizes; (void)n_in; (void)out_size;

  // ---- try cooperative mega kernel; fall back to 7-launch path on refusal --
  int blocksPerCU = 0, nCU = 0, dev = 0;
  hipError_t e1 = hipGetDevice(&dev);
  hipError_t e2 = hipDeviceGetAttribute(&nCU, hipDeviceAttributeMultiprocessorCount, dev);
  hipError_t e3 = hipOccupancyMaxActiveBlocksPerMultiprocessor(&blocksPerCU, mega_k, 256, 0);
  bool coop = (e1 == hipSuccess && e2 == hipSuccess && e3 == hipSuccess &&
               blocksPerCU >= 1 && nCU >= 1);
  if (coop){
    int grid = blocksPerCU * nCU;
    if (grid > 1000) grid = 1000;
    void* args[] = { (void*)&logits, (void*)&base, (void*)&out,
                     (void*)&XP, (void*)&BFT, (void*)&BF0, (void*)&BF1, (void*)&BF2,
                     (void*)&F1, (void*)&F2, (void*)&X1,
                     (void*)&cm, (void*)&xpart, (void*)&apart,
                     (void*)&x1part, (void*)&a2part, (void*)&part };
    hipError_t le = hipLaunchCooperativeKernel((const void*)mega_k, dim3(grid), dim3(256),
                                               args, 0, stream);
    if (le == hipSuccess) return;
  }

  // ---- fallback: R9 multi-kernel path --------------------------------------
  dim3 mmGrid(5, 5, 2*C30 + 2);
  dim3 mmAbsGrid(5, 5, 2*C30);
  dim3 baGrid(100, 10);
  dim3 prGrid(510, C30);

  fb_buildall_k<<<baGrid,256,0,stream>>>(logits, XP, BFT, BF1, BF2, xpart, apart);
  fb_mm_k<<<mmGrid,256,0,stream>>>(BF1, BF2, BFT, F1, F2, XP, apart, xpart, cm);
  fb_poolrect_k<<<prGrid,256,0,stream>>>(F1, BF0, XP, F2, cm, X1, BF2, x1part, a2part);
  fb_mm_k<<<mmGrid,256,0,stream>>>(BF0, BF2, BFT, F1, F2, XP, a2part, x1part, cm);
  fb_invrect_k<<<820,256,0,stream>>>(F1, BF1, X1, F2, cm, BF0);
  fb_mmabs_k<<<mmAbsGrid,256,0,stream>>>(BF1, BF0, BFT, XP, part);
  fb_finalize_k<<<1,256,0,stream>>>(part, base, out);
}

// Round 12
// 164.611 us; speedup vs baseline: 3.8168x; 3.8168x over previous
//
#include <hip/hip_runtime.h>
#include <math.h>

#define HP 258
#define RPAD 320
#define BSTR 328              // bf16 row stride (656B, 16B-aligned)
#define NPIX (HP*HP)
#define NPB  (RPAD*BSTR)
#define PTOT (RPAD*BSTR)
#define C30 30
#define TOT (C30*NPIX)
#define LOGW 64
#define PBLK 410              // ceil(PTOT/256)
#define CH 3

typedef __bf16 bf16x8 __attribute__((ext_vector_type(8)));
typedef float  f32x4  __attribute__((ext_vector_type(4)));
typedef unsigned short ushort;
typedef unsigned short ushort8 __attribute__((ext_vector_type(8)));

static __device__ inline ushort f2bf(float f){
  __bf16 h = (__bf16)f;
  return __builtin_bit_cast(ushort, h);
}
static __device__ inline float bf2f(ushort u){
  return (float)__builtin_bit_cast(__bf16, u);
}

// ---- swizzled-LDS MFMA read (stride 64, slot = G ^ (row&7)) ---------------
#define MM_MFMA_SWZ(KG)                                                        \
  {                                                                            \
    bf16x8 a0 = __builtin_bit_cast(bf16x8, *(const ushort8*)(&As[(wr      + l15)*64 + ((((KG)+lq) ^ (l15&7))*8)])); \
    bf16x8 a1 = __builtin_bit_cast(bf16x8, *(const ushort8*)(&As[(wr + 16 + l15)*64 + ((((KG)+lq) ^ (l15&7))*8)])); \
    bf16x8 b0 = __builtin_bit_cast(bf16x8, *(const ushort8*)(&Bs[(wc      + l15)*64 + ((((KG)+lq) ^ (l15&7))*8)])); \
    bf16x8 b1 = __builtin_bit_cast(bf16x8, *(const ushort8*)(&Bs[(wc + 16 + l15)*64 + ((((KG)+lq) ^ (l15&7))*8)])); \
    acc00 = __builtin_amdgcn_mfma_f32_16x16x32_bf16(a0, b0, acc00, 0, 0, 0);   \
    acc01 = __builtin_amdgcn_mfma_f32_16x16x32_bf16(a0, b1, acc01, 0, 0, 0);   \
    acc10 = __builtin_amdgcn_mfma_f32_16x16x32_bf16(a1, b0, acc10, 0, 0, 0);   \
    acc11 = __builtin_amdgcn_mfma_f32_16x16x32_bf16(a1, b1, acc11, 0, 0, 0);   \
  }

// ---- 72-stride MFMA read (legacy, for mm_abs) ------------------------------
#define MM_MFMA_72(KK)                                                         \
  {                                                                            \
    bf16x8 a0 = __builtin_bit_cast(bf16x8, *(const ushort8*)(&As[(wr      + l15)*72 + (KK) + lq*8])); \
    bf16x8 a1 = __builtin_bit_cast(bf16x8, *(const ushort8*)(&As[(wr + 16 + l15)*72 + (KK) + lq*8])); \
    bf16x8 b0 = __builtin_bit_cast(bf16x8, *(const ushort8*)(&Bs[(wc      + l15)*72 + (KK) + lq*8])); \
    bf16x8 b1 = __builtin_bit_cast(bf16x8, *(const ushort8*)(&Bs[(wc + 16 + l15)*72 + (KK) + lq*8])); \
    acc00 = __builtin_amdgcn_mfma_f32_16x16x32_bf16(a0, b0, acc00, 0, 0, 0);   \
    acc01 = __builtin_amdgcn_mfma_f32_16x16x32_bf16(a0, b1, acc01, 0, 0, 0);   \
    acc10 = __builtin_amdgcn_mfma_f32_16x16x32_bf16(a1, b0, acc10, 0, 0, 0);   \
    acc11 = __builtin_amdgcn_mfma_f32_16x16x32_bf16(a1, b1, acc11, 0, 0, 0);   \
  }

// ---- mm store: global_load_lds(16B) staging, swizzled source ---------------
// LDS slot (row, q) holds k-group G = q ^ (row&7); gll writes lane i's 16B at
// chunkbase + i*16 (8 rows/chunk); global src pre-swizzled so content matches.
static __device__ inline void mm_store_body(const ushort* __restrict__ Ab0,
                                            const ushort* __restrict__ Bb0,
                                            float* __restrict__ Cb,
                                            int bx, int by, int tid){
  __shared__ ushort As[64*64];
  __shared__ ushort Bs[64*64];
  int lane = tid & 63, wv = tid >> 6;
  int wvu = __builtin_amdgcn_readfirstlane(wv);
  int wr = (wv >> 1)*32, wc = (wv & 1)*32;
  int rowBase = bx*64, colBase = by*64;
  int l15 = lane & 15, lq = lane >> 4;
  f32x4 acc00 = {0.f,0.f,0.f,0.f}, acc01 = acc00, acc10 = acc00, acc11 = acc00;
  const ushort* Ab = Ab0 + (size_t)rowBase*BSTR;
  const ushort* Bb = Bb0 + (size_t)colBase*BSTR;
  int rl = lane >> 3, q = lane & 7;
  int swz8 = ((q ^ rl) & 7)*8;
  const ushort* aS = Ab + (size_t)(wvu*16 + rl)*BSTR + swz8;   // chunk pair base
  const ushort* bS = Bb + (size_t)(wvu*16 + rl)*BSTR + swz8;
  ushort* aD = As + wvu*1024;     // 2 chunks of 512 ushorts (1024B) per wave
  ushort* bD = Bs + wvu*1024;
  for (int k0 = 0; k0 < 256; k0 += 64){
    __builtin_amdgcn_global_load_lds((const void*)(aS + k0),                 (void*)aD,         16, 0, 0);
    __builtin_amdgcn_global_load_lds((const void*)(aS + (size_t)8*BSTR + k0),(void*)(aD + 512), 16, 0, 0);
    __builtin_amdgcn_global_load_lds((const void*)(bS + k0),                 (void*)bD,         16, 0, 0);
    __builtin_amdgcn_global_load_lds((const void*)(bS + (size_t)8*BSTR + k0),(void*)(bD + 512), 16, 0, 0);
    __syncthreads();
    MM_MFMA_SWZ(0);
    MM_MFMA_SWZ(4);
    __syncthreads();
  }
  {  // tail k=256..287 (reg-staged into swizzled slots; cols 258..287 zero pad)
    int row4 = tid >> 2, c84 = tid & 3;
    int tsw = ((c84 ^ (row4 & 7)) & 7)*8;
    *(ushort8*)(&As[row4*64 + tsw]) = *(const ushort8*)(Ab + (size_t)row4*BSTR + 256 + c84*8);
    *(ushort8*)(&Bs[row4*64 + tsw]) = *(const ushort8*)(Bb + (size_t)row4*BSTR + 256 + c84*8);
    __syncthreads();
    MM_MFMA_SWZ(0);
  }
  auto store = [&](f32x4 v, int r0, int c0){
    if (c0 < HP){
      #pragma unroll
      for (int r=0;r<4;r++){
        int rr = r0 + r;
        if (rr < HP) Cb[(size_t)rr*HP + c0] = v[r];
      }
    }
  };
  store(acc00, rowBase + wr +      lq*4, colBase + wc +      l15);
  store(acc01, rowBase + wr +      lq*4, colBase + wc + 16 + l15);
  store(acc10, rowBase + wr + 16 + lq*4, colBase + wc +      l15);
  store(acc11, rowBase + wr + 16 + lq*4, colBase + wc + 16 + l15);
}

// ---- mm absred: legacy reg-staged 72-stride path (unchanged, verified) -----
static __device__ inline void mm_abs_body(bool negb,
                                          const ushort* __restrict__ Ab0,
                                          const ushort* __restrict__ Bb0,
                                          const float* __restrict__ Ob,
                                          double* __restrict__ partslot,
                                          int bx, int by, int tid){
  __shared__ ushort As[64*72];
  __shared__ ushort Bs[64*72];
  __shared__ double red[256];
  int lane = tid & 63, wv = tid >> 6;
  int wr = (wv >> 1)*32, wc = (wv & 1)*32;
  int rowBase = bx*64, colBase = by*64;
  int l15 = lane & 15, lq = lane >> 4;
  f32x4 acc00 = {0.f,0.f,0.f,0.f}, acc01 = acc00, acc10 = acc00, acc11 = acc00;
  int srow = tid >> 3, sc8 = tid & 7;
  const ushort* Ab = Ab0 + (size_t)rowBase*BSTR;
  const ushort* Bb = Bb0 + (size_t)colBase*BSTR;
  const ushort* apt = Ab + (size_t)srow*BSTR + sc8*8;
  const ushort* bpt = Bb + (size_t)srow*BSTR + sc8*8;
  ushort one = f2bf(1.0f);
  auto fixB = [&](ushort8 t8, int brow, int kbase)->ushort8{
    if (!negb) return t8;
    if (brow >= HP) return t8;
    #pragma unroll
    for (int i=0;i<8;i++){
      int kk = kbase + i;
      if (kk < HP)
        t8[i] = (brow==0 || brow==HP-1 || kk==0 || kk==HP-1) ? one : (ushort)(t8[i] ^ 0x8000);
    }
    return t8;
  };
  for (int k0 = 0; k0 < 256; k0 += 64){
    *(ushort8*)(&As[srow*72 + sc8*8])      = *(const ushort8*)(apt + k0);
    *(ushort8*)(&As[(srow+32)*72 + sc8*8]) = *(const ushort8*)(apt + (size_t)32*BSTR + k0);
    *(ushort8*)(&Bs[srow*72 + sc8*8])      = fixB(*(const ushort8*)(bpt + k0), colBase + srow, k0 + sc8*8);
    *(ushort8*)(&Bs[(srow+32)*72 + sc8*8]) = fixB(*(const ushort8*)(bpt + (size_t)32*BSTR + k0), colBase + srow + 32, k0 + sc8*8);
    __syncthreads();
    MM_MFMA_72(0);
    MM_MFMA_72(32);
    __syncthreads();
  }
  {
    int row4 = tid >> 2, c84 = tid & 3;
    *(ushort8*)(&As[row4*72 + c84*8]) = *(const ushort8*)(Ab + (size_t)row4*BSTR + 256 + c84*8);
    *(ushort8*)(&Bs[row4*72 + c84*8]) = fixB(*(const ushort8*)(Bb + (size_t)row4*BSTR + 256 + c84*8), colBase + row4, 256 + c84*8);
    __syncthreads();
    MM_MFMA_72(0);
  }
  double local = 0.0;
  auto addq = [&](f32x4 v, int r0, int c0){
    if (c0 < HP){
      #pragma unroll
      for (int r=0;r<4;r++){
        int rr = r0 + r;
        if (rr < HP){
          float o = Ob[(size_t)rr*HP + c0];
          if (negb) o = (rr==0||rr==HP-1||c0==0||c0==HP-1) ? 1.0f : -o;
          local += (double)fabsf(o - v[r]);
        }
      }
    }
  };
  addq(acc00, rowBase + wr +      lq*4, colBase + wc +      l15);
  addq(acc01, rowBase + wr +      lq*4, colBase + wc + 16 + l15);
  addq(acc10, rowBase + wr + 16 + lq*4, colBase + wc +      l15);
  addq(acc11, rowBase + wr + 16 + lq*4, colBase + wc + 16 + l15);
  red[tid] = local;
  __syncthreads();
  for (int s=128; s>0; s>>=1){ if (tid<s) red[tid]+=red[tid+s]; __syncthreads(); }
  if (tid==0) *partslot = red[0];
}

// ---- cm matvec: cm = ((colsum A)@XP - colsum x)/258 ------------------------
static __device__ inline void cm_body(int ch, const float* __restrict__ apart_,
                                      const float* __restrict__ xpart_,
                                      const float* __restrict__ XPd,
                                      float* __restrict__ cmo,
                                      float* colA, int tid){
  const float* ap = apart_ + (size_t)ch*10*320;
  for (int k = tid; k < HP; k += 256){
    float s = 0.0f;
    #pragma unroll
    for (int t=0;t<10;t++) s += ap[t*320 + k];
    colA[k] = s;
  }
  __syncthreads();
  const float* xpd = XPd + (size_t)ch*NPIX;
  const float* xp2 = xpart_ + (size_t)ch*10*320;
  for (int w = tid; w < HP; w += 256){
    float acc = 0.0f;
    for (int k=0;k<HP;k++) acc = fmaf(colA[k], xpd[(size_t)k*HP + w], acc);
    float xs = 0.0f;
    #pragma unroll
    for (int t=0;t<10;t++) xs += xp2[t*320 + w];
    cmo[ch*HP + w] = (acc - xs) * (1.0f/(float)HP);
  }
}

// ---- buildall: softmax+fc+XP+BFT+pools+col partials ------------------------
__global__ __launch_bounds__(256) void fb_buildall_k(const float* __restrict__ logits,
    float* __restrict__ XP, ushort* __restrict__ BFT,
    ushort* __restrict__ BF1, ushort* __restrict__ BF2,
    float* __restrict__ xpart, float* __restrict__ apart){
  __shared__ float s6[6][34][35];
  __shared__ float fcb[34][35];
  __shared__ ushort tbuf[32][33];
  __shared__ float cr[2][8][33];
  int tile = blockIdx.x, chunk = blockIdx.y;
  int tr = tile/10, tc = tile%10;
  int r0 = tr*32, c0 = tc*32;
  int tid = threadIdx.x;
  for (int idx = tid; idx < 34*34; idx += 256){
    int lr = idx/34, lc = idx%34;
    int h = r0 - 1 + lr, w = c0 - 1 + lc;
    float sv[6];
    if (h >= 1 && h <= 256 && w >= 1 && w <= 256){
      int oh = h-1, ow = w-1;
      float fy = 0.25f*oh - 0.375f;
      float fx = 0.25f*ow - 0.375f;
      float y0f = floorf(fy), x0f = floorf(fx);
      float ty = fy - y0f, tx2 = fx - x0f;
      int y0 = max(0, (int)y0f), y1 = min(LOGW-1, (int)y0f + 1);
      int x0 = max(0, (int)x0f), x1 = min(LOGW-1, (int)x0f + 1);
      float m = -3.402823466e+38f;
      #pragma unroll
      for (int c=0;c<6;c++){
        const float* pl = logits + c*LOGW*LOGW;
        float v00 = pl[y0*LOGW + x0], v01 = pl[y0*LOGW + x1];
        float v10 = pl[y1*LOGW + x0], v11 = pl[y1*LOGW + x1];
        float a = v00 + (v01 - v00)*tx2;
        float b = v10 + (v11 - v10)*tx2;
        float v = a + (b - a)*ty;
        sv[c] = v; m = fmaxf(m, v);
      }
      float sum = 0.0f;
      #pragma unroll
      for (int c=0;c<6;c++){ sv[c] = expf(sv[c]-m); sum += sv[c]; }
      float inv = 1.0f/sum;
      #pragma unroll
      for (int c=0;c<6;c++) sv[c] *= inv;
    } else {
      #pragma unroll
      for (int c=0;c<6;c++) sv[c] = 0.0f;
    }
    #pragma unroll
    for (int c=0;c<6;c++) s6[c][lr][lc] = sv[c];
  }
  __syncthreads();
  int tx = tid & 31, rg = tid >> 5;
  for (int cc=0; cc<CH; cc++){
    int ci = chunk*CH + cc;
    int i = ci/5, r = ci%5;
    int j = r + (r>=i ? 1 : 0);
    for (int idx = tid; idx < 34*34; idx += 256){
      int lr = idx/34, lc = idx%34;
      int h = r0 - 1 + lr, w = c0 - 1 + lc;
      float v;
      if (h < 0 || h >= HP || w < 0 || w >= HP) v = 0.0f;
      else if (h==0 || h==HP-1 || w==0 || w==HP-1) v = 1.0f;
      else v = fmaxf(0.5f*(s6[i][lr][lc] - s6[j][lr][lc]), 0.0f);
      fcb[lr][lc] = v;
    }
    __syncthreads();
    float xs_acc = 0.0f, as_acc = 0.0f;
    #pragma unroll
    for (int kk=0; kk<4; kk++){
      int lrow = rg + 8*kk;
      int h = r0 + lrow, w = c0 + tx;
      int lr = lrow + 1, lc = tx + 1;
      float xpv = fcb[lr][lc];
      ushort pmaxv, pavgv, xbfv;
      if (h >= HP || w >= HP){ pmaxv = 0; pavgv = 0; xbfv = 0; }
      else if (h==0 || h==HP-1 || w==0 || w==HP-1){
        pmaxv = f2bf(1.0f); pavgv = pmaxv; xbfv = pmaxv;
        XP[(size_t)ci*NPIX + (size_t)h*HP + w] = 1.0f;
        xs_acc += 1.0f;
        as_acc += 1.0f;
      } else {
        float mv = -3.402823466e+38f, av = 0.0f;
        #pragma unroll
        for (int dy=-1;dy<=1;dy++)
          #pragma unroll
          for (int dx=-1;dx<=1;dx++){
            float nv = fcb[lr+dy][lc+dx];
            mv = fmaxf(mv, nv); av += nv;
          }
        pmaxv = f2bf(mv);
        pavgv = f2bf(av*(1.0f/9.0f));
        xbfv  = f2bf(xpv);
        XP[(size_t)ci*NPIX + (size_t)h*HP + w] = xpv;
        xs_acc += xpv;
        as_acc += bf2f(pavgv);
      }
      size_t ob = (size_t)ci*NPB + (size_t)h*BSTR + w;
      BF1[ob] = pmaxv;
      BF2[ob] = pavgv;
      tbuf[lrow][tx] = xbfv;
    }
    cr[0][rg][tx] = xs_acc;
    cr[1][rg][tx] = as_acc;
    __syncthreads();
    if (tid < 32){
      float xs = 0.0f, as = 0.0f;
      #pragma unroll
      for (int g=0; g<8; g++){ xs += cr[0][g][tid]; as += cr[1][g][tid]; }
      xpart[((size_t)ci*10 + tr)*320 + c0 + tid] = xs;
      apart[((size_t)ci*10 + tr)*320 + c0 + tid] = as;
    }
    #pragma unroll
    for (int kk=0; kk<4; kk++){
      int a = rg + 8*kk;
      BFT[(size_t)ci*NPB + (size_t)(c0+a)*BSTR + (r0 + tx)] = tbuf[tx][a];
    }
    __syncthreads();
  }
}

// ---- joint mm store + cm: z<30 op, 30..59 dil, z>=60 cm --------------------
__global__ __launch_bounds__(256) void fb_mm_k(const ushort* __restrict__ Aop,
    const ushort* __restrict__ Adil, const ushort* __restrict__ BT,
    float* __restrict__ Cop, float* __restrict__ Cdil,
    const float* __restrict__ XPd, const float* __restrict__ apart_,
    const float* __restrict__ xpart_, float* __restrict__ cmo){
  __shared__ float colA[264];
  int z = blockIdx.z;
  if (z >= 2*C30){
    int ch = (z - 2*C30)*25 + blockIdx.y*5 + blockIdx.x;
    if (ch >= C30) return;
    cm_body(ch, apart_, xpart_, XPd, cmo, colA, threadIdx.x);
    return;
  }
  bool dil = (z >= C30);
  int ch = dil ? z - C30 : z;
  mm_store_body((dil ? Adil : Aop) + (size_t)ch*NPB, BT + (size_t)ch*NPB,
                (dil ? Cdil : Cop) + (size_t)ch*NPIX,
                blockIdx.x, blockIdx.y, threadIdx.x);
}

// ---- poolrect: [bx<410] maxpool(F1)->BF0 | [else] rect+avgpool+partials ----
__global__ __launch_bounds__(256) void fb_poolrect_k(const float* __restrict__ F1,
    ushort* __restrict__ BF0, const float* __restrict__ XP,
    const float* __restrict__ F2, const float* __restrict__ cm,
    float* __restrict__ X1, ushort* __restrict__ BF2,
    float* __restrict__ x1part, float* __restrict__ a2part){
  __shared__ float rect[34][35];
  __shared__ float cr2[2][8][33];
  int ci = blockIdx.y;
  int sub = blockIdx.x;
  int tid = threadIdx.x;
  if (sub < PBLK){
    int p = sub*256 + tid;
    if (p < PTOT){
      int h = p / BSTR, w = p % BSTR;
      size_t ob = (size_t)ci*NPB + p;
      if (h >= HP || w >= HP) BF0[ob] = 0;
      else if (h==0 || h==HP-1 || w==0 || w==HP-1) BF0[ob] = f2bf(1.0f);
      else {
        const float* s = F1 + (size_t)ci*NPIX;
        float mv = -3.402823466e+38f;
        #pragma unroll
        for (int dy=-1;dy<=1;dy++){
          const float* rr = s + (size_t)(h+dy)*HP + (w-1);
          mv = fmaxf(mv, fmaxf(fmaxf(rr[0],rr[1]),rr[2]));
        }
        BF0[ob] = f2bf(mv);
      }
    }
    return;
  }
  int tl = sub - PBLK;
  int tcx = tl/10, tty = tl%10;
  int c0 = tcx*32, r0 = tty*32;
  const float* xb = XP + (size_t)ci*NPIX;
  const float* yb = F2 + (size_t)ci*NPIX;
  for (int idx = tid; idx < 34*34; idx += 256){
    int lr = idx/34, lc = idx%34;
    int h = r0 - 1 + lr, w = c0 - 1 + lc;
    float v = 0.0f;
    if (h >= 0 && h < HP && w >= 0 && w < HP){
      float xv = xb[(size_t)h*HP + w];
      float off = yb[(size_t)h*HP + w] - xv - cm[ci*HP + w];
      v = xv + fmaxf(off, 0.0f);
    }
    rect[lr][lc] = v;
  }
  __syncthreads();
  int tx = tid & 31, rg = tid >> 5;
  float xs_acc = 0.0f, as_acc = 0.0f;
  #pragma unroll
  for (int kk=0; kk<4; kk++){
    int lrow = rg + 8*kk;
    int h = r0 + lrow, w = c0 + tx;
    bool vpix = (h < HP && w < HP);
    ushort o;
    if (!vpix) o = 0;
    else {
      float xv = rect[lrow+1][tx+1];
      X1[(size_t)ci*NPIX + (size_t)h*HP + w] = xv;
      xs_acc += xv;
      if (h==0 || h==HP-1 || w==0 || w==HP-1){
        o = f2bf(1.0f);
        as_acc += 1.0f;
      } else {
        float av = (rect[lrow][tx]   + rect[lrow][tx+1]   + rect[lrow][tx+2])
                 + (rect[lrow+1][tx] + rect[lrow+1][tx+1] + rect[lrow+1][tx+2])
                 + (rect[lrow+2][tx] + rect[lrow+2][tx+1] + rect[lrow+2][tx+2]);
        o = f2bf(av*(1.0f/9.0f));
        as_acc += bf2f(o);
      }
    }
    if (h < RPAD && w < 320)
      BF2[(size_t)ci*NPB + (size_t)h*BSTR + w] = o;
  }
  cr2[0][rg][tx] = xs_acc;
  cr2[1][rg][tx] = as_acc;
  __syncthreads();
  if (tid < 32){
    float xs = 0.0f, as = 0.0f;
    #pragma unroll
    for (int g=0; g<8; g++){ xs += cr2[0][g][tid]; as += cr2[1][g][tid]; }
    x1part[((size_t)ci*10 + tty)*320 + c0 + tid] = xs;
    a2part[((size_t)ci*10 + tty)*320 + c0 + tid] = as;
  }
}

// ---- invrect: [bx<410] invnorm(F1)->An | [else] rect+invnorm->An2 ----------
__global__ __launch_bounds__(256) void fb_invrect_k(const float* __restrict__ F1,
    ushort* __restrict__ An, const float* __restrict__ X1,
    const float* __restrict__ F2, const float* __restrict__ cm,
    ushort* __restrict__ An2){
  bool second = (blockIdx.x >= PBLK);
  int p = (second ? blockIdx.x - PBLK : (int)blockIdx.x)*256 + threadIdx.x;
  if (p >= PTOT) return;
  int h = p / BSTR, w = p % BSTR;
  ushort* dst = second ? An2 : An;
  if (h >= HP || w >= HP){
    #pragma unroll
    for (int c=0;c<C30;c++) dst[(size_t)c*NPB+p] = 0;
    return;
  }
  int pd = h*HP + w;
  float v[C30];
  float ss = 0.0f;
  if (!second){
    #pragma unroll
    for (int c=0;c<C30;c++){ v[c] = F1[(size_t)c*NPIX+pd]; ss = fmaf(v[c],v[c],ss); }
  } else {
    #pragma unroll
    for (int c=0;c<C30;c++){
      float xv = X1[(size_t)c*NPIX + pd];
      float off = F2[(size_t)c*NPIX + pd] - xv - cm[c*HP + w];
      float vv = xv + fmaxf(off, 0.0f);
      v[c] = vv;
      ss = fmaf(vv, vv, ss);
    }
  }
  float n = sqrtf(2.0f*ss);
  float inv = 1.0f / fmaxf(n, 1e-12f);
  #pragma unroll
  for (int c=0;c<C30;c++) dst[(size_t)c*NPB+p] = f2bf(v[c]*inv);
}

// ---- joint mm absred -------------------------------------------------------
__global__ __launch_bounds__(256) void fb_mmabs_k(const ushort* __restrict__ Aop,
    const ushort* __restrict__ Adil, const ushort* __restrict__ BT,
    const float* __restrict__ XPop, double* __restrict__ part){
  int z = blockIdx.z;
  bool negb = (z < C30);
  int ch = negb ? z : z - C30;
  mm_abs_body(negb, (negb ? Aop : Adil) + (size_t)ch*NPB, BT + (size_t)ch*NPB,
              XPop + (size_t)ch*NPIX, &part[(size_t)z*25 + blockIdx.y*5 + blockIdx.x],
              blockIdx.x, blockIdx.y, threadIdx.x);
}

__global__ void fb_finalize_k(const double* __restrict__ part,
                              const float* __restrict__ base, float* __restrict__ out){
  __shared__ double s0[256], s1[256];
  int tid = threadIdx.x;
  double l0=0.0, l1=0.0;
  for (int i=tid;i<750;i+=256){ l0 += part[i]; l1 += part[750+i]; }
  s0[tid]=l0; s1[tid]=l1; __syncthreads();
  for (int s=128;s>0;s>>=1){ if (tid<s){ s0[tid]+=s0[tid+s]; s1[tid]+=s1[tid+s]; } __syncthreads(); }
  if (tid==0) out[0] = (float)(fabs(2.0*(s0[0]-s1[0])) + (double)base[0]);
}

extern "C" void kernel_launch(void* const* d_in, const int* in_sizes, int n_in,
                              void* d_out, int out_size, void* d_ws, size_t ws_size,
                              hipStream_t stream){
  const float* logits = (const float*)d_in[0];
  const float* base   = (const float*)d_in[1];
  float* out = (float*)d_out;

  char* ws = (char*)d_ws;
  size_t off = 0;
  auto alloc = [&](size_t bytes)->char*{
    char* p = ws + off; off = (off + bytes + 255) & ~(size_t)255; return p;
  };
  double* part    = (double*)alloc(1500*sizeof(double));
  float*  cm      = (float*) alloc((size_t)C30*HP*sizeof(float));
  float*  xpart   = (float*) alloc((size_t)C30*10*320*sizeof(float));
  float*  apart   = (float*) alloc((size_t)C30*10*320*sizeof(float));
  float*  x1part  = (float*) alloc((size_t)C30*10*320*sizeof(float));
  float*  a2part  = (float*) alloc((size_t)C30*10*320*sizeof(float));
  float*  XP      = (float*) alloc((size_t)TOT*sizeof(float));
  ushort* BF0     = (ushort*)alloc((size_t)C30*NPB*sizeof(ushort));
  ushort* BFT     = (ushort*)alloc((size_t)C30*NPB*sizeof(ushort));
  ushort* BF1     = (ushort*)alloc((size_t)C30*NPB*sizeof(ushort));
  ushort* BF2     = (ushort*)alloc((size_t)C30*NPB*sizeof(ushort));
  float*  F1      = (float*) alloc((size_t)TOT*sizeof(float));
  float*  F2      = (float*) alloc((size_t)TOT*sizeof(float));
  float*  X1      = (float*) alloc((size_t)TOT*sizeof(float));
  (void)ws_size; (void)in_sizes; (void)n_in; (void)out_size;

  dim3 mmGrid(5, 5, 2*C30 + 2);
  dim3 mmAbsGrid(5, 5, 2*C30);
  dim3 baGrid(100, 10);
  dim3 prGrid(510, C30);

  fb_buildall_k<<<baGrid,256,0,stream>>>(logits, XP, BFT, BF1, BF2, xpart, apart);
  fb_mm_k<<<mmGrid,256,0,stream>>>(BF1, BF2, BFT, F1, F2, XP, apart, xpart, cm);
  fb_poolrect_k<<<prGrid,256,0,stream>>>(F1, BF0, XP, F2, cm, X1, BF2, x1part, a2part);
  fb_mm_k<<<mmGrid,256,0,stream>>>(BF0, BF2, BFT, F1, F2, XP, a2part, x1part, cm);
  fb_invrect_k<<<820,256,0,stream>>>(F1, BF1, X1, F2, cm, BF0);
  fb_mmabs_k<<<mmAbsGrid,256,0,stream>>>(BF1, BF0, BFT, XP, part);
  fb_finalize_k<<<1,256,0,stream>>>(part, base, out);
}

// Round 13
// 137.681 us; speedup vs baseline: 4.5634x; 1.1956x over previous
//
#include <hip/hip_runtime.h>
#include <math.h>

#define HP 258
#define RPAD 320
#define BSTR 328              // bf16 row stride (656B, 16B-aligned)
#define NPIX (HP*HP)
#define NPB  (RPAD*BSTR)
#define PTOT (RPAD*BSTR)
#define C30 30
#define TOT (C30*NPIX)
#define LOGW 64
#define PBLK 410              // ceil(PTOT/256)
#define CH 3

typedef __bf16 bf16x8 __attribute__((ext_vector_type(8)));
typedef float  f32x4  __attribute__((ext_vector_type(4)));
typedef unsigned short ushort;
typedef unsigned short ushort8 __attribute__((ext_vector_type(8)));

static __device__ inline ushort f2bf(float f){
  __bf16 h = (__bf16)f;
  return __builtin_bit_cast(ushort, h);
}
static __device__ inline float bf2f(ushort u){
  return (float)__builtin_bit_cast(__bf16, u);
}

// ---- bijective XCD swizzle (m204): hardware id -> work id ------------------
// XCD k = orig%8 processes a CONTIGUOUS chunk of work ids -> per-XCD L2 reuse.
static __device__ inline int xcd_swz(int orig, int nwg){
  int xcd = orig & 7, s = orig >> 3;
  int q = nwg >> 3, r = nwg & 7;
  return (xcd < r ? xcd*(q+1) : r*(q+1) + (xcd - r)*q) + s;
}

#define MM_MFMA_72(KK)                                                         \
  {                                                                            \
    bf16x8 a0 = __builtin_bit_cast(bf16x8, *(const ushort8*)(&As[(wr      + l15)*72 + (KK) + lq*8])); \
    bf16x8 a1 = __builtin_bit_cast(bf16x8, *(const ushort8*)(&As[(wr + 16 + l15)*72 + (KK) + lq*8])); \
    bf16x8 b0 = __builtin_bit_cast(bf16x8, *(const ushort8*)(&Bs[(wc      + l15)*72 + (KK) + lq*8])); \
    bf16x8 b1 = __builtin_bit_cast(bf16x8, *(const ushort8*)(&Bs[(wc + 16 + l15)*72 + (KK) + lq*8])); \
    acc00 = __builtin_amdgcn_mfma_f32_16x16x32_bf16(a0, b0, acc00, 0, 0, 0);   \
    acc01 = __builtin_amdgcn_mfma_f32_16x16x32_bf16(a0, b1, acc01, 0, 0, 0);   \
    acc10 = __builtin_amdgcn_mfma_f32_16x16x32_bf16(a1, b0, acc10, 0, 0, 0);   \
    acc11 = __builtin_amdgcn_mfma_f32_16x16x32_bf16(a1, b1, acc11, 0, 0, 0);   \
  }

// ---- mm store: reg-staged 72-stride (R9-verified) --------------------------
static __device__ inline void mm_store_body(const ushort* __restrict__ Ab0,
                                            const ushort* __restrict__ Bb0,
                                            float* __restrict__ Cb,
                                            int bx, int by, int tid,
                                            ushort* As, ushort* Bs){
  int lane = tid & 63, wv = tid >> 6;
  int wr = (wv >> 1)*32, wc = (wv & 1)*32;
  int rowBase = bx*64, colBase = by*64;
  int l15 = lane & 15, lq = lane >> 4;
  f32x4 acc00 = {0.f,0.f,0.f,0.f}, acc01 = acc00, acc10 = acc00, acc11 = acc00;
  int srow = tid >> 3, sc8 = tid & 7;
  const ushort* Ab = Ab0 + (size_t)rowBase*BSTR;
  const ushort* Bb = Bb0 + (size_t)colBase*BSTR;
  const ushort* apt = Ab + (size_t)srow*BSTR + sc8*8;
  const ushort* bpt = Bb + (size_t)srow*BSTR + sc8*8;
  for (int k0 = 0; k0 < 256; k0 += 64){
    *(ushort8*)(&As[srow*72 + sc8*8])      = *(const ushort8*)(apt + k0);
    *(ushort8*)(&As[(srow+32)*72 + sc8*8]) = *(const ushort8*)(apt + (size_t)32*BSTR + k0);
    *(ushort8*)(&Bs[srow*72 + sc8*8])      = *(const ushort8*)(bpt + k0);
    *(ushort8*)(&Bs[(srow+32)*72 + sc8*8]) = *(const ushort8*)(bpt + (size_t)32*BSTR + k0);
    __syncthreads();
    MM_MFMA_72(0);
    MM_MFMA_72(32);
    __syncthreads();
  }
  {  // tail k=256..287 (zero pad beyond 258)
    int row4 = tid >> 2, c84 = tid & 3;
    *(ushort8*)(&As[row4*72 + c84*8]) = *(const ushort8*)(Ab + (size_t)row4*BSTR + 256 + c84*8);
    *(ushort8*)(&Bs[row4*72 + c84*8]) = *(const ushort8*)(Bb + (size_t)row4*BSTR + 256 + c84*8);
    __syncthreads();
    MM_MFMA_72(0);
  }
  auto store = [&](f32x4 v, int r0, int c0){
    if (c0 < HP){
      #pragma unroll
      for (int r=0;r<4;r++){
        int rr = r0 + r;
        if (rr < HP) Cb[(size_t)rr*HP + c0] = v[r];
      }
    }
  };
  store(acc00, rowBase + wr +      lq*4, colBase + wc +      l15);
  store(acc01, rowBase + wr +      lq*4, colBase + wc + 16 + l15);
  store(acc10, rowBase + wr + 16 + lq*4, colBase + wc +      l15);
  store(acc11, rowBase + wr + 16 + lq*4, colBase + wc + 16 + l15);
}

// ---- mm absred: reg-staged 72-stride (verified) ----------------------------
static __device__ inline void mm_abs_body(bool negb,
                                          const ushort* __restrict__ Ab0,
                                          const ushort* __restrict__ Bb0,
                                          const float* __restrict__ Ob,
                                          double* __restrict__ partslot,
                                          int bx, int by, int tid,
                                          ushort* As, ushort* Bs, double* red){
  int lane = tid & 63, wv = tid >> 6;
  int wr = (wv >> 1)*32, wc = (wv & 1)*32;
  int rowBase = bx*64, colBase = by*64;
  int l15 = lane & 15, lq = lane >> 4;
  f32x4 acc00 = {0.f,0.f,0.f,0.f}, acc01 = acc00, acc10 = acc00, acc11 = acc00;
  int srow = tid >> 3, sc8 = tid & 7;
  const ushort* Ab = Ab0 + (size_t)rowBase*BSTR;
  const ushort* Bb = Bb0 + (size_t)colBase*BSTR;
  const ushort* apt = Ab + (size_t)srow*BSTR + sc8*8;
  const ushort* bpt = Bb + (size_t)srow*BSTR + sc8*8;
  ushort one = f2bf(1.0f);
  auto fixB = [&](ushort8 t8, int brow, int kbase)->ushort8{
    if (!negb) return t8;
    if (brow >= HP) return t8;
    #pragma unroll
    for (int i=0;i<8;i++){
      int kk = kbase + i;
      if (kk < HP)
        t8[i] = (brow==0 || brow==HP-1 || kk==0 || kk==HP-1) ? one : (ushort)(t8[i] ^ 0x8000);
    }
    return t8;
  };
  for (int k0 = 0; k0 < 256; k0 += 64){
    *(ushort8*)(&As[srow*72 + sc8*8])      = *(const ushort8*)(apt + k0);
    *(ushort8*)(&As[(srow+32)*72 + sc8*8]) = *(const ushort8*)(apt + (size_t)32*BSTR + k0);
    *(ushort8*)(&Bs[srow*72 + sc8*8])      = fixB(*(const ushort8*)(bpt + k0), colBase + srow, k0 + sc8*8);
    *(ushort8*)(&Bs[(srow+32)*72 + sc8*8]) = fixB(*(const ushort8*)(bpt + (size_t)32*BSTR + k0), colBase + srow + 32, k0 + sc8*8);
    __syncthreads();
    MM_MFMA_72(0);
    MM_MFMA_72(32);
    __syncthreads();
  }
  {
    int row4 = tid >> 2, c84 = tid & 3;
    *(ushort8*)(&As[row4*72 + c84*8]) = *(const ushort8*)(Ab + (size_t)row4*BSTR + 256 + c84*8);
    *(ushort8*)(&Bs[row4*72 + c84*8]) = fixB(*(const ushort8*)(Bb + (size_t)row4*BSTR + 256 + c84*8), colBase + row4, 256 + c84*8);
    __syncthreads();
    MM_MFMA_72(0);
  }
  double local = 0.0;
  auto addq = [&](f32x4 v, int r0, int c0){
    if (c0 < HP){
      #pragma unroll
      for (int r=0;r<4;r++){
        int rr = r0 + r;
        if (rr < HP){
          float o = Ob[(size_t)rr*HP + c0];
          if (negb) o = (rr==0||rr==HP-1||c0==0||c0==HP-1) ? 1.0f : -o;
          local += (double)fabsf(o - v[r]);
        }
      }
    }
  };
  addq(acc00, rowBase + wr +      lq*4, colBase + wc +      l15);
  addq(acc01, rowBase + wr +      lq*4, colBase + wc + 16 + l15);
  addq(acc10, rowBase + wr + 16 + lq*4, colBase + wc +      l15);
  addq(acc11, rowBase + wr + 16 + lq*4, colBase + wc + 16 + l15);
  red[tid] = local;
  __syncthreads();
  for (int s=128; s>0; s>>=1){ if (tid<s) red[tid]+=red[tid+s]; __syncthreads(); }
  if (tid==0) *partslot = red[0];
}

// ---- cm matvec: cm = ((colsum A)@XP - colsum x)/258 ------------------------
static __device__ inline void cm_body(int ch, const float* __restrict__ apart_,
                                      const float* __restrict__ xpart_,
                                      const float* __restrict__ XPd,
                                      float* __restrict__ cmo,
                                      float* colA, int tid){
  const float* ap = apart_ + (size_t)ch*10*320;
  for (int k = tid; k < HP; k += 256){
    float s = 0.0f;
    #pragma unroll
    for (int t=0;t<10;t++) s += ap[t*320 + k];
    colA[k] = s;
  }
  __syncthreads();
  const float* xpd = XPd + (size_t)ch*NPIX;
  const float* xp2 = xpart_ + (size_t)ch*10*320;
  for (int w = tid; w < HP; w += 256){
    float acc = 0.0f;
    for (int k=0;k<HP;k++) acc = fmaf(colA[k], xpd[(size_t)k*HP + w], acc);
    float xs = 0.0f;
    #pragma unroll
    for (int t=0;t<10;t++) xs += xp2[t*320 + w];
    cmo[ch*HP + w] = (acc - xs) * (1.0f/(float)HP);
  }
}

// ---- buildall: softmax+fc+XP+BFT+pools+col partials ------------------------
__global__ __launch_bounds__(256) void fb_buildall_k(const float* __restrict__ logits,
    float* __restrict__ XP, ushort* __restrict__ BFT,
    ushort* __restrict__ BF1, ushort* __restrict__ BF2,
    float* __restrict__ xpart, float* __restrict__ apart){
  __shared__ float s6[6][34][35];
  __shared__ float fcb[34][35];
  __shared__ ushort tbuf[32][33];
  __shared__ float cr[2][8][33];
  int tile = blockIdx.x, chunk = blockIdx.y;
  int tr = tile/10, tc = tile%10;
  int r0 = tr*32, c0 = tc*32;
  int tid = threadIdx.x;
  for (int idx = tid; idx < 34*34; idx += 256){
    int lr = idx/34, lc = idx%34;
    int h = r0 - 1 + lr, w = c0 - 1 + lc;
    float sv[6];
    if (h >= 1 && h <= 256 && w >= 1 && w <= 256){
      int oh = h-1, ow = w-1;
      float fy = 0.25f*oh - 0.375f;
      float fx = 0.25f*ow - 0.375f;
      float y0f = floorf(fy), x0f = floorf(fx);
      float ty = fy - y0f, tx2 = fx - x0f;
      int y0 = max(0, (int)y0f), y1 = min(LOGW-1, (int)y0f + 1);
      int x0 = max(0, (int)x0f), x1 = min(LOGW-1, (int)x0f + 1);
      float m = -3.402823466e+38f;
      #pragma unroll
      for (int c=0;c<6;c++){
        const float* pl = logits + c*LOGW*LOGW;
        float v00 = pl[y0*LOGW + x0], v01 = pl[y0*LOGW + x1];
        float v10 = pl[y1*LOGW + x0], v11 = pl[y1*LOGW + x1];
        float a = v00 + (v01 - v00)*tx2;
        float b = v10 + (v11 - v10)*tx2;
        float v = a + (b - a)*ty;
        sv[c] = v; m = fmaxf(m, v);
      }
      float sum = 0.0f;
      #pragma unroll
      for (int c=0;c<6;c++){ sv[c] = expf(sv[c]-m); sum += sv[c]; }
      float inv = 1.0f/sum;
      #pragma unroll
      for (int c=0;c<6;c++) sv[c] *= inv;
    } else {
      #pragma unroll
      for (int c=0;c<6;c++) sv[c] = 0.0f;
    }
    #pragma unroll
    for (int c=0;c<6;c++) s6[c][lr][lc] = sv[c];
  }
  __syncthreads();
  int tx = tid & 31, rg = tid >> 5;
  for (int cc=0; cc<CH; cc++){
    int ci = chunk*CH + cc;
    int i = ci/5, r = ci%5;
    int j = r + (r>=i ? 1 : 0);
    for (int idx = tid; idx < 34*34; idx += 256){
      int lr = idx/34, lc = idx%34;
      int h = r0 - 1 + lr, w = c0 - 1 + lc;
      float v;
      if (h < 0 || h >= HP || w < 0 || w >= HP) v = 0.0f;
      else if (h==0 || h==HP-1 || w==0 || w==HP-1) v = 1.0f;
      else v = fmaxf(0.5f*(s6[i][lr][lc] - s6[j][lr][lc]), 0.0f);
      fcb[lr][lc] = v;
    }
    __syncthreads();
    float xs_acc = 0.0f, as_acc = 0.0f;
    #pragma unroll
    for (int kk=0; kk<4; kk++){
      int lrow = rg + 8*kk;
      int h = r0 + lrow, w = c0 + tx;
      int lr = lrow + 1, lc = tx + 1;
      float xpv = fcb[lr][lc];
      ushort pmaxv, pavgv, xbfv;
      if (h >= HP || w >= HP){ pmaxv = 0; pavgv = 0; xbfv = 0; }
      else if (h==0 || h==HP-1 || w==0 || w==HP-1){
        pmaxv = f2bf(1.0f); pavgv = pmaxv; xbfv = pmaxv;
        XP[(size_t)ci*NPIX + (size_t)h*HP + w] = 1.0f;
        xs_acc += 1.0f;
        as_acc += 1.0f;
      } else {
        float mv = -3.402823466e+38f, av = 0.0f;
        #pragma unroll
        for (int dy=-1;dy<=1;dy++)
          #pragma unroll
          for (int dx=-1;dx<=1;dx++){
            float nv = fcb[lr+dy][lc+dx];
            mv = fmaxf(mv, nv); av += nv;
          }
        pmaxv = f2bf(mv);
        pavgv = f2bf(av*(1.0f/9.0f));
        xbfv  = f2bf(xpv);
        XP[(size_t)ci*NPIX + (size_t)h*HP + w] = xpv;
        xs_acc += xpv;
        as_acc += bf2f(pavgv);
      }
      size_t ob = (size_t)ci*NPB + (size_t)h*BSTR + w;
      BF1[ob] = pmaxv;
      BF2[ob] = pavgv;
      tbuf[lrow][tx] = xbfv;
    }
    cr[0][rg][tx] = xs_acc;
    cr[1][rg][tx] = as_acc;
    __syncthreads();
    if (tid < 32){
      float xs = 0.0f, as = 0.0f;
      #pragma unroll
      for (int g=0; g<8; g++){ xs += cr[0][g][tid]; as += cr[1][g][tid]; }
      xpart[((size_t)ci*10 + tr)*320 + c0 + tid] = xs;
      apart[((size_t)ci*10 + tr)*320 + c0 + tid] = as;
    }
    #pragma unroll
    for (int kk=0; kk<4; kk++){
      int a = rg + 8*kk;
      BFT[(size_t)ci*NPB + (size_t)(c0+a)*BSTR + (r0 + tx)] = tbuf[tx][a];
    }
    __syncthreads();
  }
}

// ---- joint mm store + cm: 1D grid 1530, XCD-swizzled -----------------------
__global__ __launch_bounds__(256) void fb_mm_k(const ushort* __restrict__ Aop,
    const ushort* __restrict__ Adil, const ushort* __restrict__ BT,
    float* __restrict__ Cop, float* __restrict__ Cdil,
    const float* __restrict__ XPd, const float* __restrict__ apart_,
    const float* __restrict__ xpart_, float* __restrict__ cmo){
  __shared__ ushort As[64*72];
  __shared__ ushort Bs[64*72];
  int wg = xcd_swz(blockIdx.x, 1530);
  if (wg >= 1500){
    cm_body(wg - 1500, apart_, xpart_, XPd, cmo, (float*)As, threadIdx.x);
    return;
  }
  int bx = wg % 5, by = (wg/5) % 5, z = wg/25;   // z-major: 25 consecutive wg per channel
  bool dil = (z >= C30);
  int ch = dil ? z - C30 : z;
  mm_store_body((dil ? Adil : Aop) + (size_t)ch*NPB, BT + (size_t)ch*NPB,
                (dil ? Cdil : Cop) + (size_t)ch*NPIX,
                bx, by, threadIdx.x, As, Bs);
}

// ---- poolrect: [bx<410] maxpool(F1)->BF0 | [else] rect+avgpool+partials ----
__global__ __launch_bounds__(256) void fb_poolrect_k(const float* __restrict__ F1,
    ushort* __restrict__ BF0, const float* __restrict__ XP,
    const float* __restrict__ F2, const float* __restrict__ cm,
    float* __restrict__ X1, ushort* __restrict__ BF2,
    float* __restrict__ x1part, float* __restrict__ a2part){
  __shared__ float rect[34][35];
  __shared__ float cr2[2][8][33];
  int ci = blockIdx.y;
  int sub = blockIdx.x;
  int tid = threadIdx.x;
  if (sub < PBLK){
    int p = sub*256 + tid;
    if (p < PTOT){
      int h = p / BSTR, w = p % BSTR;
      size_t ob = (size_t)ci*NPB + p;
      if (h >= HP || w >= HP) BF0[ob] = 0;
      else if (h==0 || h==HP-1 || w==0 || w==HP-1) BF0[ob] = f2bf(1.0f);
      else {
        const float* s = F1 + (size_t)ci*NPIX;
        float mv = -3.402823466e+38f;
        #pragma unroll
        for (int dy=-1;dy<=1;dy++){
          const float* rr = s + (size_t)(h+dy)*HP + (w-1);
          mv = fmaxf(mv, fmaxf(fmaxf(rr[0],rr[1]),rr[2]));
        }
        BF0[ob] = f2bf(mv);
      }
    }
    return;
  }
  int tl = sub - PBLK;
  int tcx = tl/10, tty = tl%10;
  int c0 = tcx*32, r0 = tty*32;
  const float* xb = XP + (size_t)ci*NPIX;
  const float* yb = F2 + (size_t)ci*NPIX;
  for (int idx = tid; idx < 34*34; idx += 256){
    int lr = idx/34, lc = idx%34;
    int h = r0 - 1 + lr, w = c0 - 1 + lc;
    float v = 0.0f;
    if (h >= 0 && h < HP && w >= 0 && w < HP){
      float xv = xb[(size_t)h*HP + w];
      float off = yb[(size_t)h*HP + w] - xv - cm[ci*HP + w];
      v = xv + fmaxf(off, 0.0f);
    }
    rect[lr][lc] = v;
  }
  __syncthreads();
  int tx = tid & 31, rg = tid >> 5;
  float xs_acc = 0.0f, as_acc = 0.0f;
  #pragma unroll
  for (int kk=0; kk<4; kk++){
    int lrow = rg + 8*kk;
    int h = r0 + lrow, w = c0 + tx;
    bool vpix = (h < HP && w < HP);
    ushort o;
    if (!vpix) o = 0;
    else {
      float xv = rect[lrow+1][tx+1];
      X1[(size_t)ci*NPIX + (size_t)h*HP + w] = xv;
      xs_acc += xv;
      if (h==0 || h==HP-1 || w==0 || w==HP-1){
        o = f2bf(1.0f);
        as_acc += 1.0f;
      } else {
        float av = (rect[lrow][tx]   + rect[lrow][tx+1]   + rect[lrow][tx+2])
                 + (rect[lrow+1][tx] + rect[lrow+1][tx+1] + rect[lrow+1][tx+2])
                 + (rect[lrow+2][tx] + rect[lrow+2][tx+1] + rect[lrow+2][tx+2]);
        o = f2bf(av*(1.0f/9.0f));
        as_acc += bf2f(o);
      }
    }
    if (h < RPAD && w < 320)
      BF2[(size_t)ci*NPB + (size_t)h*BSTR + w] = o;
  }
  cr2[0][rg][tx] = xs_acc;
  cr2[1][rg][tx] = as_acc;
  __syncthreads();
  if (tid < 32){
    float xs = 0.0f, as = 0.0f;
    #pragma unroll
    for (int g=0; g<8; g++){ xs += cr2[0][g][tid]; as += cr2[1][g][tid]; }
    x1part[((size_t)ci*10 + tty)*320 + c0 + tid] = xs;
    a2part[((size_t)ci*10 + tty)*320 + c0 + tid] = as;
  }
}

// ---- invrect: [bx<410] invnorm(F1)->An | [else] rect+invnorm->An2 ----------
__global__ __launch_bounds__(256) void fb_invrect_k(const float* __restrict__ F1,
    ushort* __restrict__ An, const float* __restrict__ X1,
    const float* __restrict__ F2, const float* __restrict__ cm,
    ushort* __restrict__ An2){
  bool second = (blockIdx.x >= PBLK);
  int p = (second ? blockIdx.x - PBLK : (int)blockIdx.x)*256 + threadIdx.x;
  if (p >= PTOT) return;
  int h = p / BSTR, w = p % BSTR;
  ushort* dst = second ? An2 : An;
  if (h >= HP || w >= HP){
    #pragma unroll
    for (int c=0;c<C30;c++) dst[(size_t)c*NPB+p] = 0;
    return;
  }
  int pd = h*HP + w;
  float v[C30];
  float ss = 0.0f;
  if (!second){
    #pragma unroll
    for (int c=0;c<C30;c++){ v[c] = F1[(size_t)c*NPIX+pd]; ss = fmaf(v[c],v[c],ss); }
  } else {
    #pragma unroll
    for (int c=0;c<C30;c++){
      float xv = X1[(size_t)c*NPIX + pd];
      float off = F2[(size_t)c*NPIX + pd] - xv - cm[c*HP + w];
      float vv = xv + fmaxf(off, 0.0f);
      v[c] = vv;
      ss = fmaf(vv, vv, ss);
    }
  }
  float n = sqrtf(2.0f*ss);
  float inv = 1.0f / fmaxf(n, 1e-12f);
  #pragma unroll
  for (int c=0;c<C30;c++) dst[(size_t)c*NPB+p] = f2bf(v[c]*inv);
}

// ---- joint mm absred: 1D grid 1500, XCD-swizzled ---------------------------
__global__ __launch_bounds__(256) void fb_mmabs_k(const ushort* __restrict__ Aop,
    const ushort* __restrict__ Adil, const ushort* __restrict__ BT,
    const float* __restrict__ XPop, double* __restrict__ part){
  __shared__ ushort As[64*72];
  __shared__ ushort Bs[64*72];
  __shared__ double red[256];
  int wg = xcd_swz(blockIdx.x, 1500);
  int bx = wg % 5, by = (wg/5) % 5, z = wg/25;
  bool negb = (z < C30);
  int ch = negb ? z : z - C30;
  mm_abs_body(negb, (negb ? Aop : Adil) + (size_t)ch*NPB, BT + (size_t)ch*NPB,
              XPop + (size_t)ch*NPIX, &part[(size_t)z*25 + by*5 + bx],
              bx, by, threadIdx.x, As, Bs, red);
}

__global__ void fb_finalize_k(const double* __restrict__ part,
                              const float* __restrict__ base, float* __restrict__ out){
  __shared__ double s0[256], s1[256];
  int tid = threadIdx.x;
  double l0=0.0, l1=0.0;
  for (int i=tid;i<750;i+=256){ l0 += part[i]; l1 += part[750+i]; }
  s0[tid]=l0; s1[tid]=l1; __syncthreads();
  for (int s=128;s>0;s>>=1){ if (tid<s){ s0[tid]+=s0[tid+s]; s1[tid]+=s1[tid+s]; } __syncthreads(); }
  if (tid==0) out[0] = (float)(fabs(2.0*(s0[0]-s1[0])) + (double)base[0]);
}

extern "C" void kernel_launch(void* const* d_in, const int* in_sizes, int n_in,
                              void* d_out, int out_size, void* d_ws, size_t ws_size,
                              hipStream_t stream){
  const float* logits = (const float*)d_in[0];
  const float* base   = (const float*)d_in[1];
  float* out = (float*)d_out;

  char* ws = (char*)d_ws;
  size_t off = 0;
  auto alloc = [&](size_t bytes)->char*{
    char* p = ws + off; off = (off + bytes + 255) & ~(size_t)255; return p;
  };
  double* part    = (double*)alloc(1500*sizeof(double));
  float*  cm      = (float*) alloc((size_t)C30*HP*sizeof(float));
  float*  xpart   = (float*) alloc((size_t)C30*10*320*sizeof(float));
  float*  apart   = (float*) alloc((size_t)C30*10*320*sizeof(float));
  float*  x1part  = (float*) alloc((size_t)C30*10*320*sizeof(float));
  float*  a2part  = (float*) alloc((size_t)C30*10*320*sizeof(float));
  float*  XP      = (float*) alloc((size_t)TOT*sizeof(float));
  ushort* BF0     = (ushort*)alloc((size_t)C30*NPB*sizeof(ushort));
  ushort* BFT     = (ushort*)alloc((size_t)C30*NPB*sizeof(ushort));
  ushort* BF1     = (ushort*)alloc((size_t)C30*NPB*sizeof(ushort));
  ushort* BF2     = (ushort*)alloc((size_t)C30*NPB*sizeof(ushort));
  float*  F1      = (float*) alloc((size_t)TOT*sizeof(float));
  float*  F2      = (float*) alloc((size_t)TOT*sizeof(float));
  float*  X1      = (float*) alloc((size_t)TOT*sizeof(float));
  (void)ws_size; (void)in_sizes; (void)n_in; (void)out_size;

  dim3 baGrid(100, 10);
  dim3 prGrid(510, C30);

  fb_buildall_k<<<baGrid,256,0,stream>>>(logits, XP, BFT, BF1, BF2, xpart, apart);
  fb_mm_k<<<1530,256,0,stream>>>(BF1, BF2, BFT, F1, F2, XP, apart, xpart, cm);
  fb_poolrect_k<<<prGrid,256,0,stream>>>(F1, BF0, XP, F2, cm, X1, BF2, x1part, a2part);
  fb_mm_k<<<1530,256,0,stream>>>(BF0, BF2, BFT, F1, F2, XP, a2part, x1part, cm);
  fb_invrect_k<<<820,256,0,stream>>>(F1, BF1, X1, F2, cm, BF0);
  fb_mmabs_k<<<1500,256,0,stream>>>(BF1, BF0, BFT, XP, part);
  fb_finalize_k<<<1,256,0,stream>>>(part, base, out);
}

// Round 14
// 131.472 us; speedup vs baseline: 4.7789x; 1.0472x over previous
//
#include <hip/hip_runtime.h>
#include <math.h>

#define HP 258
#define RPAD 320
#define BSTR 328              // bf16 row stride (656B, 16B-aligned)
#define NPIX (HP*HP)
#define NPB  (RPAD*BSTR)
#define PTOT (RPAD*BSTR)
#define C30 30
#define TOT (C30*NPIX)
#define LOGW 64
#define PBLK 410
#define CH 3

typedef __bf16 bf16x8 __attribute__((ext_vector_type(8)));
typedef float  f32x4  __attribute__((ext_vector_type(4)));
typedef unsigned short ushort;
typedef unsigned short ushort8 __attribute__((ext_vector_type(8)));

static __device__ inline ushort f2bf(float f){
  __bf16 h = (__bf16)f;
  return __builtin_bit_cast(ushort, h);
}
static __device__ inline float bf2f(ushort u){
  return (float)__builtin_bit_cast(__bf16, u);
}

// ---- bijective XCD swizzle (m204): hardware id -> work id ------------------
static __device__ inline int xcd_swz(int orig, int nwg){
  int xcd = orig & 7, s = orig >> 3;
  int q = nwg >> 3, r = nwg & 7;
  return (xcd < r ? xcd*(q+1) : r*(q+1) + (xcd - r)*q) + s;
}

#define MM_MFMA_72(KK)                                                         \
  {                                                                            \
    bf16x8 a0 = __builtin_bit_cast(bf16x8, *(const ushort8*)(&As[(wr      + l15)*72 + (KK) + lq*8])); \
    bf16x8 a1 = __builtin_bit_cast(bf16x8, *(const ushort8*)(&As[(wr + 16 + l15)*72 + (KK) + lq*8])); \
    bf16x8 b0 = __builtin_bit_cast(bf16x8, *(const ushort8*)(&Bs[(wc      + l15)*72 + (KK) + lq*8])); \
    bf16x8 b1 = __builtin_bit_cast(bf16x8, *(const ushort8*)(&Bs[(wc + 16 + l15)*72 + (KK) + lq*8])); \
    acc00 = __builtin_amdgcn_mfma_f32_16x16x32_bf16(a0, b0, acc00, 0, 0, 0);   \
    acc01 = __builtin_amdgcn_mfma_f32_16x16x32_bf16(a0, b1, acc01, 0, 0, 0);   \
    acc10 = __builtin_amdgcn_mfma_f32_16x16x32_bf16(a1, b0, acc10, 0, 0, 0);   \
    acc11 = __builtin_amdgcn_mfma_f32_16x16x32_bf16(a1, b1, acc11, 0, 0, 0);   \
  }

// paired variant: two A-tiles (As1, As2) share b0/b1
#define MM_MFMA_PAIR(KK)                                                       \
  {                                                                            \
    bf16x8 b0 = __builtin_bit_cast(bf16x8, *(const ushort8*)(&Bs[(wc      + l15)*72 + (KK) + lq*8])); \
    bf16x8 b1 = __builtin_bit_cast(bf16x8, *(const ushort8*)(&Bs[(wc + 16 + l15)*72 + (KK) + lq*8])); \
    bf16x8 a0 = __builtin_bit_cast(bf16x8, *(const ushort8*)(&As1[(wr      + l15)*72 + (KK) + lq*8])); \
    bf16x8 a1 = __builtin_bit_cast(bf16x8, *(const ushort8*)(&As1[(wr + 16 + l15)*72 + (KK) + lq*8])); \
    p00 = __builtin_amdgcn_mfma_f32_16x16x32_bf16(a0, b0, p00, 0, 0, 0);       \
    p01 = __builtin_amdgcn_mfma_f32_16x16x32_bf16(a0, b1, p01, 0, 0, 0);       \
    p10 = __builtin_amdgcn_mfma_f32_16x16x32_bf16(a1, b0, p10, 0, 0, 0);       \
    p11 = __builtin_amdgcn_mfma_f32_16x16x32_bf16(a1, b1, p11, 0, 0, 0);       \
    a0 = __builtin_bit_cast(bf16x8, *(const ushort8*)(&As2[(wr      + l15)*72 + (KK) + lq*8])); \
    a1 = __builtin_bit_cast(bf16x8, *(const ushort8*)(&As2[(wr + 16 + l15)*72 + (KK) + lq*8])); \
    q00 = __builtin_amdgcn_mfma_f32_16x16x32_bf16(a0, b0, q00, 0, 0, 0);       \
    q01 = __builtin_amdgcn_mfma_f32_16x16x32_bf16(a0, b1, q01, 0, 0, 0);       \
    q10 = __builtin_amdgcn_mfma_f32_16x16x32_bf16(a1, b0, q10, 0, 0, 0);       \
    q11 = __builtin_amdgcn_mfma_f32_16x16x32_bf16(a1, b1, q11, 0, 0, 0);       \
  }

// ---- paired mm store: Cop = Aop@B^T, Cdil = Adil@B^T (B staged once) -------
static __device__ inline void mm_pair_body(const ushort* __restrict__ A1b,
                                           const ushort* __restrict__ A2b,
                                           const ushort* __restrict__ Bb0,
                                           float* __restrict__ C1b,
                                           float* __restrict__ C2b,
                                           int bx, int by, int tid,
                                           ushort* As1, ushort* As2, ushort* Bs){
  int lane = tid & 63, wv = tid >> 6;
  int wr = (wv >> 1)*32, wc = (wv & 1)*32;
  int rowBase = bx*64, colBase = by*64;
  int l15 = lane & 15, lq = lane >> 4;
  f32x4 p00 = {0.f,0.f,0.f,0.f}, p01 = p00, p10 = p00, p11 = p00;
  f32x4 q00 = p00, q01 = p00, q10 = p00, q11 = p00;
  int srow = tid >> 3, sc8 = tid & 7;
  const ushort* A1 = A1b + (size_t)rowBase*BSTR;
  const ushort* A2 = A2b + (size_t)rowBase*BSTR;
  const ushort* Bb = Bb0 + (size_t)colBase*BSTR;
  const ushort* a1p = A1 + (size_t)srow*BSTR + sc8*8;
  const ushort* a2p = A2 + (size_t)srow*BSTR + sc8*8;
  const ushort* bpt = Bb + (size_t)srow*BSTR + sc8*8;
  for (int k0 = 0; k0 < 256; k0 += 64){
    *(ushort8*)(&As1[srow*72 + sc8*8])      = *(const ushort8*)(a1p + k0);
    *(ushort8*)(&As1[(srow+32)*72 + sc8*8]) = *(const ushort8*)(a1p + (size_t)32*BSTR + k0);
    *(ushort8*)(&As2[srow*72 + sc8*8])      = *(const ushort8*)(a2p + k0);
    *(ushort8*)(&As2[(srow+32)*72 + sc8*8]) = *(const ushort8*)(a2p + (size_t)32*BSTR + k0);
    *(ushort8*)(&Bs[srow*72 + sc8*8])       = *(const ushort8*)(bpt + k0);
    *(ushort8*)(&Bs[(srow+32)*72 + sc8*8])  = *(const ushort8*)(bpt + (size_t)32*BSTR + k0);
    __syncthreads();
    MM_MFMA_PAIR(0);
    MM_MFMA_PAIR(32);
    __syncthreads();
  }
  {  // tail k=256..287 (zero pad beyond 258)
    int row4 = tid >> 2, c84 = tid & 3;
    *(ushort8*)(&As1[row4*72 + c84*8]) = *(const ushort8*)(A1 + (size_t)row4*BSTR + 256 + c84*8);
    *(ushort8*)(&As2[row4*72 + c84*8]) = *(const ushort8*)(A2 + (size_t)row4*BSTR + 256 + c84*8);
    *(ushort8*)(&Bs[row4*72 + c84*8])  = *(const ushort8*)(Bb + (size_t)row4*BSTR + 256 + c84*8);
    __syncthreads();
    MM_MFMA_PAIR(0);
  }
  auto store = [&](float* Cb, f32x4 v, int r0, int c0){
    if (c0 < HP){
      #pragma unroll
      for (int r=0;r<4;r++){
        int rr = r0 + r;
        if (rr < HP) Cb[(size_t)rr*HP + c0] = v[r];
      }
    }
  };
  store(C1b, p00, rowBase + wr +      lq*4, colBase + wc +      l15);
  store(C1b, p01, rowBase + wr +      lq*4, colBase + wc + 16 + l15);
  store(C1b, p10, rowBase + wr + 16 + lq*4, colBase + wc +      l15);
  store(C1b, p11, rowBase + wr + 16 + lq*4, colBase + wc + 16 + l15);
  store(C2b, q00, rowBase + wr +      lq*4, colBase + wc +      l15);
  store(C2b, q01, rowBase + wr +      lq*4, colBase + wc + 16 + l15);
  store(C2b, q10, rowBase + wr + 16 + lq*4, colBase + wc +      l15);
  store(C2b, q11, rowBase + wr + 16 + lq*4, colBase + wc + 16 + l15);
}

// ---- mm absred: reg-staged 72-stride (verified, unchanged) -----------------
static __device__ inline void mm_abs_body(bool negb,
                                          const ushort* __restrict__ Ab0,
                                          const ushort* __restrict__ Bb0,
                                          const float* __restrict__ Ob,
                                          double* __restrict__ partslot,
                                          int bx, int by, int tid,
                                          ushort* As, ushort* Bs, double* red){
  int lane = tid & 63, wv = tid >> 6;
  int wr = (wv >> 1)*32, wc = (wv & 1)*32;
  int rowBase = bx*64, colBase = by*64;
  int l15 = lane & 15, lq = lane >> 4;
  f32x4 acc00 = {0.f,0.f,0.f,0.f}, acc01 = acc00, acc10 = acc00, acc11 = acc00;
  int srow = tid >> 3, sc8 = tid & 7;
  const ushort* Ab = Ab0 + (size_t)rowBase*BSTR;
  const ushort* Bb = Bb0 + (size_t)colBase*BSTR;
  const ushort* apt = Ab + (size_t)srow*BSTR + sc8*8;
  const ushort* bpt = Bb + (size_t)srow*BSTR + sc8*8;
  ushort one = f2bf(1.0f);
  auto fixB = [&](ushort8 t8, int brow, int kbase)->ushort8{
    if (!negb) return t8;
    if (brow >= HP) return t8;
    #pragma unroll
    for (int i=0;i<8;i++){
      int kk = kbase + i;
      if (kk < HP)
        t8[i] = (brow==0 || brow==HP-1 || kk==0 || kk==HP-1) ? one : (ushort)(t8[i] ^ 0x8000);
    }
    return t8;
  };
  for (int k0 = 0; k0 < 256; k0 += 64){
    *(ushort8*)(&As[srow*72 + sc8*8])      = *(const ushort8*)(apt + k0);
    *(ushort8*)(&As[(srow+32)*72 + sc8*8]) = *(const ushort8*)(apt + (size_t)32*BSTR + k0);
    *(ushort8*)(&Bs[srow*72 + sc8*8])      = fixB(*(const ushort8*)(bpt + k0), colBase + srow, k0 + sc8*8);
    *(ushort8*)(&Bs[(srow+32)*72 + sc8*8]) = fixB(*(const ushort8*)(bpt + (size_t)32*BSTR + k0), colBase + srow + 32, k0 + sc8*8);
    __syncthreads();
    MM_MFMA_72(0);
    MM_MFMA_72(32);
    __syncthreads();
  }
  {
    int row4 = tid >> 2, c84 = tid & 3;
    *(ushort8*)(&As[row4*72 + c84*8]) = *(const ushort8*)(Ab + (size_t)row4*BSTR + 256 + c84*8);
    *(ushort8*)(&Bs[row4*72 + c84*8]) = fixB(*(const ushort8*)(Bb + (size_t)row4*BSTR + 256 + c84*8), colBase + row4, 256 + c84*8);
    __syncthreads();
    MM_MFMA_72(0);
  }
  double local = 0.0;
  auto addq = [&](f32x4 v, int r0, int c0){
    if (c0 < HP){
      #pragma unroll
      for (int r=0;r<4;r++){
        int rr = r0 + r;
        if (rr < HP){
          float o = Ob[(size_t)rr*HP + c0];
          if (negb) o = (rr==0||rr==HP-1||c0==0||c0==HP-1) ? 1.0f : -o;
          local += (double)fabsf(o - v[r]);
        }
      }
    }
  };
  addq(acc00, rowBase + wr +      lq*4, colBase + wc +      l15);
  addq(acc01, rowBase + wr +      lq*4, colBase + wc + 16 + l15);
  addq(acc10, rowBase + wr + 16 + lq*4, colBase + wc +      l15);
  addq(acc11, rowBase + wr + 16 + lq*4, colBase + wc + 16 + l15);
  red[tid] = local;
  __syncthreads();
  for (int s=128; s>0; s>>=1){ if (tid<s) red[tid]+=red[tid+s]; __syncthreads(); }
  if (tid==0) *partslot = red[0];
}

// ---- cm matvec: cm = ((colsum A)@XP - colsum x)/258 ------------------------
static __device__ inline void cm_body(int ch, const float* __restrict__ apart_,
                                      const float* __restrict__ xpart_,
                                      const float* __restrict__ XPd,
                                      float* __restrict__ cmo,
                                      float* colA, int tid){
  const float* ap = apart_ + (size_t)ch*10*320;
  for (int k = tid; k < HP; k += 256){
    float s = 0.0f;
    #pragma unroll
    for (int t=0;t<10;t++) s += ap[t*320 + k];
    colA[k] = s;
  }
  __syncthreads();
  const float* xpd = XPd + (size_t)ch*NPIX;
  const float* xp2 = xpart_ + (size_t)ch*10*320;
  for (int w = tid; w < HP; w += 256){
    float acc = 0.0f;
    for (int k=0;k<HP;k++) acc = fmaf(colA[k], xpd[(size_t)k*HP + w], acc);
    float xs = 0.0f;
    #pragma unroll
    for (int t=0;t<10;t++) xs += xp2[t*320 + w];
    cmo[ch*HP + w] = (acc - xs) * (1.0f/(float)HP);
  }
}

// ---- buildall: softmax+fc+XP+BFT+pools+col partials (unchanged) ------------
__global__ __launch_bounds__(256) void fb_buildall_k(const float* __restrict__ logits,
    float* __restrict__ XP, ushort* __restrict__ BFT,
    ushort* __restrict__ BF1, ushort* __restrict__ BF2,
    float* __restrict__ xpart, float* __restrict__ apart){
  __shared__ float s6[6][34][35];
  __shared__ float fcb[34][35];
  __shared__ ushort tbuf[32][33];
  __shared__ float cr[2][8][33];
  int tile = blockIdx.x, chunk = blockIdx.y;
  int tr = tile/10, tc = tile%10;
  int r0 = tr*32, c0 = tc*32;
  int tid = threadIdx.x;
  for (int idx = tid; idx < 34*34; idx += 256){
    int lr = idx/34, lc = idx%34;
    int h = r0 - 1 + lr, w = c0 - 1 + lc;
    float sv[6];
    if (h >= 1 && h <= 256 && w >= 1 && w <= 256){
      int oh = h-1, ow = w-1;
      float fy = 0.25f*oh - 0.375f;
      float fx = 0.25f*ow - 0.375f;
      float y0f = floorf(fy), x0f = floorf(fx);
      float ty = fy - y0f, tx2 = fx - x0f;
      int y0 = max(0, (int)y0f), y1 = min(LOGW-1, (int)y0f + 1);
      int x0 = max(0, (int)x0f), x1 = min(LOGW-1, (int)x0f + 1);
      float m = -3.402823466e+38f;
      #pragma unroll
      for (int c=0;c<6;c++){
        const float* pl = logits + c*LOGW*LOGW;
        float v00 = pl[y0*LOGW + x0], v01 = pl[y0*LOGW + x1];
        float v10 = pl[y1*LOGW + x0], v11 = pl[y1*LOGW + x1];
        float a = v00 + (v01 - v00)*tx2;
        float b = v10 + (v11 - v10)*tx2;
        float v = a + (b - a)*ty;
        sv[c] = v; m = fmaxf(m, v);
      }
      float sum = 0.0f;
      #pragma unroll
      for (int c=0;c<6;c++){ sv[c] = expf(sv[c]-m); sum += sv[c]; }
      float inv = 1.0f/sum;
      #pragma unroll
      for (int c=0;c<6;c++) sv[c] *= inv;
    } else {
      #pragma unroll
      for (int c=0;c<6;c++) sv[c] = 0.0f;
    }
    #pragma unroll
    for (int c=0;c<6;c++) s6[c][lr][lc] = sv[c];
  }
  __syncthreads();
  int tx = tid & 31, rg = tid >> 5;
  for (int cc=0; cc<CH; cc++){
    int ci = chunk*CH + cc;
    int i = ci/5, r = ci%5;
    int j = r + (r>=i ? 1 : 0);
    for (int idx = tid; idx < 34*34; idx += 256){
      int lr = idx/34, lc = idx%34;
      int h = r0 - 1 + lr, w = c0 - 1 + lc;
      float v;
      if (h < 0 || h >= HP || w < 0 || w >= HP) v = 0.0f;
      else if (h==0 || h==HP-1 || w==0 || w==HP-1) v = 1.0f;
      else v = fmaxf(0.5f*(s6[i][lr][lc] - s6[j][lr][lc]), 0.0f);
      fcb[lr][lc] = v;
    }
    __syncthreads();
    float xs_acc = 0.0f, as_acc = 0.0f;
    #pragma unroll
    for (int kk=0; kk<4; kk++){
      int lrow = rg + 8*kk;
      int h = r0 + lrow, w = c0 + tx;
      int lr = lrow + 1, lc = tx + 1;
      float xpv = fcb[lr][lc];
      ushort pmaxv, pavgv, xbfv;
      if (h >= HP || w >= HP){ pmaxv = 0; pavgv = 0; xbfv = 0; }
      else if (h==0 || h==HP-1 || w==0 || w==HP-1){
        pmaxv = f2bf(1.0f); pavgv = pmaxv; xbfv = pmaxv;
        XP[(size_t)ci*NPIX + (size_t)h*HP + w] = 1.0f;
        xs_acc += 1.0f;
        as_acc += 1.0f;
      } else {
        float mv = -3.402823466e+38f, av = 0.0f;
        #pragma unroll
        for (int dy=-1;dy<=1;dy++)
          #pragma unroll
          for (int dx=-1;dx<=1;dx++){
            float nv = fcb[lr+dy][lc+dx];
            mv = fmaxf(mv, nv); av += nv;
          }
        pmaxv = f2bf(mv);
        pavgv = f2bf(av*(1.0f/9.0f));
        xbfv  = f2bf(xpv);
        XP[(size_t)ci*NPIX + (size_t)h*HP + w] = xpv;
        xs_acc += xpv;
        as_acc += bf2f(pavgv);
      }
      size_t ob = (size_t)ci*NPB + (size_t)h*BSTR + w;
      BF1[ob] = pmaxv;
      BF2[ob] = pavgv;
      tbuf[lrow][tx] = xbfv;
    }
    cr[0][rg][tx] = xs_acc;
    cr[1][rg][tx] = as_acc;
    __syncthreads();
    if (tid < 32){
      float xs = 0.0f, as = 0.0f;
      #pragma unroll
      for (int g=0; g<8; g++){ xs += cr[0][g][tid]; as += cr[1][g][tid]; }
      xpart[((size_t)ci*10 + tr)*320 + c0 + tid] = xs;
      apart[((size_t)ci*10 + tr)*320 + c0 + tid] = as;
    }
    #pragma unroll
    for (int kk=0; kk<4; kk++){
      int a = rg + 8*kk;
      BFT[(size_t)ci*NPB + (size_t)(c0+a)*BSTR + (r0 + tx)] = tbuf[tx][a];
    }
    __syncthreads();
  }
}

// ---- paired mm store + cm: 1D grid 780, XCD-swizzled -----------------------
__global__ __launch_bounds__(256) void fb_mm_k(const ushort* __restrict__ Aop,
    const ushort* __restrict__ Adil, const ushort* __restrict__ BT,
    float* __restrict__ Cop, float* __restrict__ Cdil,
    const float* __restrict__ XPd, const float* __restrict__ apart_,
    const float* __restrict__ xpart_, float* __restrict__ cmo){
  __shared__ ushort As1[64*72];
  __shared__ ushort As2[64*72];
  __shared__ ushort Bs[64*72];
  int wg = xcd_swz(blockIdx.x, 780);
  if (wg >= 750){
    cm_body(wg - 750, apart_, xpart_, XPd, cmo, (float*)As1, threadIdx.x);
    return;
  }
  int bx = wg % 5, by = (wg/5) % 5, ch = wg/25;   // 25 consecutive wg per channel
  mm_pair_body(Aop + (size_t)ch*NPB, Adil + (size_t)ch*NPB, BT + (size_t)ch*NPB,
               Cop + (size_t)ch*NPIX, Cdil + (size_t)ch*NPIX,
               bx, by, threadIdx.x, As1, As2, Bs);
}

// ---- tile-fused poolrect: maxpool(F1)->BF0 AND rect+avgpool per tile -------
__global__ __launch_bounds__(256) void fb_poolrect_k(const float* __restrict__ F1,
    ushort* __restrict__ BF0, const float* __restrict__ XP,
    const float* __restrict__ F2, const float* __restrict__ cm,
    float* __restrict__ X1, ushort* __restrict__ BF2,
    float* __restrict__ x1part, float* __restrict__ a2part){
  __shared__ float rect[34][35];
  __shared__ float cr2[2][8][33];
  int ci = blockIdx.y;
  int tl = blockIdx.x;
  int tcx = tl/10, tty = tl%10;
  int c0 = tcx*32, r0 = tty*32;
  int tid = threadIdx.x;
  int tx = tid & 31, rg = tid >> 5;
  // ---- job A: maxpool(F1) -> BF0 (tile + halo via LDS) ----
  {
    const float* fb = F1 + (size_t)ci*NPIX;
    for (int idx = tid; idx < 34*34; idx += 256){
      int lr = idx/34, lc = idx%34;
      int h = r0 - 1 + lr, w = c0 - 1 + lc;
      rect[lr][lc] = (h >= 0 && h < HP && w >= 0 && w < HP) ? fb[(size_t)h*HP + w] : 0.0f;
    }
    __syncthreads();
    #pragma unroll
    for (int kk=0; kk<4; kk++){
      int lrow = rg + 8*kk;
      int h = r0 + lrow, w = c0 + tx;
      ushort o;
      if (h >= HP || w >= HP) o = 0;
      else if (h==0 || h==HP-1 || w==0 || w==HP-1) o = f2bf(1.0f);
      else {
        float mv = fmaxf(fmaxf(rect[lrow][tx],   rect[lrow][tx+1]),   rect[lrow][tx+2]);
        mv = fmaxf(mv, fmaxf(fmaxf(rect[lrow+1][tx], rect[lrow+1][tx+1]), rect[lrow+1][tx+2]));
        mv = fmaxf(mv, fmaxf(fmaxf(rect[lrow+2][tx], rect[lrow+2][tx+1]), rect[lrow+2][tx+2]));
        o = f2bf(mv);
      }
      BF0[(size_t)ci*NPB + (size_t)h*BSTR + w] = o;
    }
    __syncthreads();
  }
  // ---- job B: rect(XP,F2,cm) -> X1; avgpool -> BF2; col partials ----
  const float* xb = XP + (size_t)ci*NPIX;
  const float* yb = F2 + (size_t)ci*NPIX;
  for (int idx = tid; idx < 34*34; idx += 256){
    int lr = idx/34, lc = idx%34;
    int h = r0 - 1 + lr, w = c0 - 1 + lc;
    float v = 0.0f;
    if (h >= 0 && h < HP && w >= 0 && w < HP){
      float xv = xb[(size_t)h*HP + w];
      float off = yb[(size_t)h*HP + w] - xv - cm[ci*HP + w];
      v = xv + fmaxf(off, 0.0f);
    }
    rect[lr][lc] = v;
  }
  __syncthreads();
  float xs_acc = 0.0f, as_acc = 0.0f;
  #pragma unroll
  for (int kk=0; kk<4; kk++){
    int lrow = rg + 8*kk;
    int h = r0 + lrow, w = c0 + tx;
    bool vpix = (h < HP && w < HP);
    ushort o;
    if (!vpix) o = 0;
    else {
      float xv = rect[lrow+1][tx+1];
      X1[(size_t)ci*NPIX + (size_t)h*HP + w] = xv;
      xs_acc += xv;
      if (h==0 || h==HP-1 || w==0 || w==HP-1){
        o = f2bf(1.0f);
        as_acc += 1.0f;
      } else {
        float av = (rect[lrow][tx]   + rect[lrow][tx+1]   + rect[lrow][tx+2])
                 + (rect[lrow+1][tx] + rect[lrow+1][tx+1] + rect[lrow+1][tx+2])
                 + (rect[lrow+2][tx] + rect[lrow+2][tx+1] + rect[lrow+2][tx+2]);
        o = f2bf(av*(1.0f/9.0f));
        as_acc += bf2f(o);
      }
    }
    BF2[(size_t)ci*NPB + (size_t)h*BSTR + w] = o;
  }
  cr2[0][rg][tx] = xs_acc;
  cr2[1][rg][tx] = as_acc;
  __syncthreads();
  if (tid < 32){
    float xs = 0.0f, as = 0.0f;
    #pragma unroll
    for (int g=0; g<8; g++){ xs += cr2[0][g][tid]; as += cr2[1][g][tid]; }
    x1part[((size_t)ci*10 + tty)*320 + c0 + tid] = xs;
    a2part[((size_t)ci*10 + tty)*320 + c0 + tid] = as;
  }
}

// ---- invrect: [bx<410] invnorm(F1)->An | [else] rect+invnorm->An2 ----------
__global__ __launch_bounds__(256) void fb_invrect_k(const float* __restrict__ F1,
    ushort* __restrict__ An, const float* __restrict__ X1,
    const float* __restrict__ F2, const float* __restrict__ cm,
    ushort* __restrict__ An2){
  bool second = (blockIdx.x >= PBLK);
  int p = (second ? blockIdx.x - PBLK : (int)blockIdx.x)*256 + threadIdx.x;
  if (p >= PTOT) return;
  int h = p / BSTR, w = p % BSTR;
  ushort* dst = second ? An2 : An;
  if (h >= HP || w >= HP){
    #pragma unroll
    for (int c=0;c<C30;c++) dst[(size_t)c*NPB+p] = 0;
    return;
  }
  int pd = h*HP + w;
  float v[C30];
  float ss = 0.0f;
  if (!second){
    #pragma unroll
    for (int c=0;c<C30;c++){ v[c] = F1[(size_t)c*NPIX+pd]; ss = fmaf(v[c],v[c],ss); }
  } else {
    #pragma unroll
    for (int c=0;c<C30;c++){
      float xv = X1[(size_t)c*NPIX + pd];
      float off = F2[(size_t)c*NPIX + pd] - xv - cm[c*HP + w];
      float vv = xv + fmaxf(off, 0.0f);
      v[c] = vv;
      ss = fmaf(vv, vv, ss);
    }
  }
  float n = sqrtf(2.0f*ss);
  float inv = 1.0f / fmaxf(n, 1e-12f);
  #pragma unroll
  for (int c=0;c<C30;c++) dst[(size_t)c*NPB+p] = f2bf(v[c]*inv);
}

// ---- joint mm absred: 1D grid 1500, XCD-swizzled ---------------------------
__global__ __launch_bounds__(256) void fb_mmabs_k(const ushort* __restrict__ Aop,
    const ushort* __restrict__ Adil, const ushort* __restrict__ BT,
    const float* __restrict__ XPop, double* __restrict__ part){
  __shared__ ushort As[64*72];
  __shared__ ushort Bs[64*72];
  __shared__ double red[256];
  int wg = xcd_swz(blockIdx.x, 1500);
  int bx = wg % 5, by = (wg/5) % 5, z = wg/25;
  bool negb = (z < C30);
  int ch = negb ? z : z - C30;
  mm_abs_body(negb, (negb ? Aop : Adil) + (size_t)ch*NPB, BT + (size_t)ch*NPB,
              XPop + (size_t)ch*NPIX, &part[(size_t)z*25 + by*5 + bx],
              bx, by, threadIdx.x, As, Bs, red);
}

__global__ void fb_finalize_k(const double* __restrict__ part,
                              const float* __restrict__ base, float* __restrict__ out){
  __shared__ double s0[256], s1[256];
  int tid = threadIdx.x;
  double l0=0.0, l1=0.0;
  for (int i=tid;i<750;i+=256){ l0 += part[i]; l1 += part[750+i]; }
  s0[tid]=l0; s1[tid]=l1; __syncthreads();
  for (int s=128;s>0;s>>=1){ if (tid<s){ s0[tid]+=s0[tid+s]; s1[tid]+=s1[tid+s]; } __syncthreads(); }
  if (tid==0) out[0] = (float)(fabs(2.0*(s0[0]-s1[0])) + (double)base[0]);
}

extern "C" void kernel_launch(void* const* d_in, const int* in_sizes, int n_in,
                              void* d_out, int out_size, void* d_ws, size_t ws_size,
                              hipStream_t stream){
  const float* logits = (const float*)d_in[0];
  const float* base   = (const float*)d_in[1];
  float* out = (float*)d_out;

  char* ws = (char*)d_ws;
  size_t off = 0;
  auto alloc = [&](size_t bytes)->char*{
    char* p = ws + off; off = (off + bytes + 255) & ~(size_t)255; return p;
  };
  double* part    = (double*)alloc(1500*sizeof(double));
  float*  cm      = (float*) alloc((size_t)C30*HP*sizeof(float));
  float*  xpart   = (float*) alloc((size_t)C30*10*320*sizeof(float));
  float*  apart   = (float*) alloc((size_t)C30*10*320*sizeof(float));
  float*  x1part  = (float*) alloc((size_t)C30*10*320*sizeof(float));
  float*  a2part  = (float*) alloc((size_t)C30*10*320*sizeof(float));
  float*  XP      = (float*) alloc((size_t)TOT*sizeof(float));
  ushort* BF0     = (ushort*)alloc((size_t)C30*NPB*sizeof(ushort));
  ushort* BFT     = (ushort*)alloc((size_t)C30*NPB*sizeof(ushort));
  ushort* BF1     = (ushort*)alloc((size_t)C30*NPB*sizeof(ushort));
  ushort* BF2     = (ushort*)alloc((size_t)C30*NPB*sizeof(ushort));
  float*  F1      = (float*) alloc((size_t)TOT*sizeof(float));
  float*  F2      = (float*) alloc((size_t)TOT*sizeof(float));
  float*  X1      = (float*) alloc((size_t)TOT*sizeof(float));
  (void)ws_size; (void)in_sizes; (void)n_in; (void)out_size;

  dim3 baGrid(100, 10);
  dim3 prGrid(100, C30);

  fb_buildall_k<<<baGrid,256,0,stream>>>(logits, XP, BFT, BF1, BF2, xpart, apart);
  fb_mm_k<<<780,256,0,stream>>>(BF1, BF2, BFT, F1, F2, XP, apart, xpart, cm);
  fb_poolrect_k<<<prGrid,256,0,stream>>>(F1, BF0, XP, F2, cm, X1, BF2, x1part, a2part);
  fb_mm_k<<<780,256,0,stream>>>(BF0, BF2, BFT, F1, F2, XP, a2part, x1part, cm);
  fb_invrect_k<<<820,256,0,stream>>>(F1, BF1, X1, F2, cm, BF0);
  fb_mmabs_k<<<1500,256,0,stream>>>(BF1, BF0, BFT, XP, part);
  fb_finalize_k<<<1,256,0,stream>>>(part, base, out);
}

// Round 15
// 129.976 us; speedup vs baseline: 4.8339x; 1.0115x over previous
//
#include <hip/hip_runtime.h>
#include <math.h>

#define HP 258
#define RPAD 320
#define BSTR 328              // bf16 row stride (656B, 16B-aligned)
#define NPIX (HP*HP)
#define NPB  (RPAD*BSTR)
#define PTOT (RPAD*BSTR)
#define C30 30
#define TOT (C30*NPIX)
#define LOGW 64
#define PBLK 410
#define CH 3

typedef __bf16 bf16x8 __attribute__((ext_vector_type(8)));
typedef float  f32x4  __attribute__((ext_vector_type(4)));
typedef unsigned short ushort;
typedef unsigned short ushort8 __attribute__((ext_vector_type(8)));

static __device__ inline ushort f2bf(float f){
  __bf16 h = (__bf16)f;
  return __builtin_bit_cast(ushort, h);
}
static __device__ inline float bf2f(ushort u){
  return (float)__builtin_bit_cast(__bf16, u);
}

// ---- bijective XCD swizzle (m204): hardware id -> work id ------------------
static __device__ inline int xcd_swz(int orig, int nwg){
  int xcd = orig & 7, s = orig >> 3;
  int q = nwg >> 3, r = nwg & 7;
  return (xcd < r ? xcd*(q+1) : r*(q+1) + (xcd - r)*q) + s;
}

// paired store variant: two A-tiles (As1, As2) share b0/b1 from one Bs
#define MM_MFMA_PAIR(KK)                                                       \
  {                                                                            \
    bf16x8 b0 = __builtin_bit_cast(bf16x8, *(const ushort8*)(&Bs[(wc      + l15)*72 + (KK) + lq*8])); \
    bf16x8 b1 = __builtin_bit_cast(bf16x8, *(const ushort8*)(&Bs[(wc + 16 + l15)*72 + (KK) + lq*8])); \
    bf16x8 a0 = __builtin_bit_cast(bf16x8, *(const ushort8*)(&As1[(wr      + l15)*72 + (KK) + lq*8])); \
    bf16x8 a1 = __builtin_bit_cast(bf16x8, *(const ushort8*)(&As1[(wr + 16 + l15)*72 + (KK) + lq*8])); \
    p00 = __builtin_amdgcn_mfma_f32_16x16x32_bf16(a0, b0, p00, 0, 0, 0);       \
    p01 = __builtin_amdgcn_mfma_f32_16x16x32_bf16(a0, b1, p01, 0, 0, 0);       \
    p10 = __builtin_amdgcn_mfma_f32_16x16x32_bf16(a1, b0, p10, 0, 0, 0);       \
    p11 = __builtin_amdgcn_mfma_f32_16x16x32_bf16(a1, b1, p11, 0, 0, 0);       \
    a0 = __builtin_bit_cast(bf16x8, *(const ushort8*)(&As2[(wr      + l15)*72 + (KK) + lq*8])); \
    a1 = __builtin_bit_cast(bf16x8, *(const ushort8*)(&As2[(wr + 16 + l15)*72 + (KK) + lq*8])); \
    q00 = __builtin_amdgcn_mfma_f32_16x16x32_bf16(a0, b0, q00, 0, 0, 0);       \
    q01 = __builtin_amdgcn_mfma_f32_16x16x32_bf16(a0, b1, q01, 0, 0, 0);       \
    q10 = __builtin_amdgcn_mfma_f32_16x16x32_bf16(a1, b0, q10, 0, 0, 0);       \
    q11 = __builtin_amdgcn_mfma_f32_16x16x32_bf16(a1, b1, q11, 0, 0, 0);       \
  }

// paired absred variant: p uses BsN (negated/opening), q uses BsP (plain/dil)
#define MM_MFMA_ABSPAIR(KK)                                                    \
  {                                                                            \
    bf16x8 b0 = __builtin_bit_cast(bf16x8, *(const ushort8*)(&BsN[(wc      + l15)*72 + (KK) + lq*8])); \
    bf16x8 b1 = __builtin_bit_cast(bf16x8, *(const ushort8*)(&BsN[(wc + 16 + l15)*72 + (KK) + lq*8])); \
    bf16x8 a0 = __builtin_bit_cast(bf16x8, *(const ushort8*)(&As1[(wr      + l15)*72 + (KK) + lq*8])); \
    bf16x8 a1 = __builtin_bit_cast(bf16x8, *(const ushort8*)(&As1[(wr + 16 + l15)*72 + (KK) + lq*8])); \
    p00 = __builtin_amdgcn_mfma_f32_16x16x32_bf16(a0, b0, p00, 0, 0, 0);       \
    p01 = __builtin_amdgcn_mfma_f32_16x16x32_bf16(a0, b1, p01, 0, 0, 0);       \
    p10 = __builtin_amdgcn_mfma_f32_16x16x32_bf16(a1, b0, p10, 0, 0, 0);       \
    p11 = __builtin_amdgcn_mfma_f32_16x16x32_bf16(a1, b1, p11, 0, 0, 0);       \
    b0 = __builtin_bit_cast(bf16x8, *(const ushort8*)(&BsP[(wc      + l15)*72 + (KK) + lq*8])); \
    b1 = __builtin_bit_cast(bf16x8, *(const ushort8*)(&BsP[(wc + 16 + l15)*72 + (KK) + lq*8])); \
    a0 = __builtin_bit_cast(bf16x8, *(const ushort8*)(&As2[(wr      + l15)*72 + (KK) + lq*8])); \
    a1 = __builtin_bit_cast(bf16x8, *(const ushort8*)(&As2[(wr + 16 + l15)*72 + (KK) + lq*8])); \
    q00 = __builtin_amdgcn_mfma_f32_16x16x32_bf16(a0, b0, q00, 0, 0, 0);       \
    q01 = __builtin_amdgcn_mfma_f32_16x16x32_bf16(a0, b1, q01, 0, 0, 0);       \
    q10 = __builtin_amdgcn_mfma_f32_16x16x32_bf16(a1, b0, q10, 0, 0, 0);       \
    q11 = __builtin_amdgcn_mfma_f32_16x16x32_bf16(a1, b1, q11, 0, 0, 0);       \
  }

// ---- paired mm store: Cop = Aop@B^T, Cdil = Adil@B^T (B staged once) -------
static __device__ inline void mm_pair_body(const ushort* __restrict__ A1b,
                                           const ushort* __restrict__ A2b,
                                           const ushort* __restrict__ Bb0,
                                           float* __restrict__ C1b,
                                           float* __restrict__ C2b,
                                           int bx, int by, int tid,
                                           ushort* As1, ushort* As2, ushort* Bs){
  int lane = tid & 63, wv = tid >> 6;
  int wr = (wv >> 1)*32, wc = (wv & 1)*32;
  int rowBase = bx*64, colBase = by*64;
  int l15 = lane & 15, lq = lane >> 4;
  f32x4 p00 = {0.f,0.f,0.f,0.f}, p01 = p00, p10 = p00, p11 = p00;
  f32x4 q00 = p00, q01 = p00, q10 = p00, q11 = p00;
  int srow = tid >> 3, sc8 = tid & 7;
  const ushort* A1 = A1b + (size_t)rowBase*BSTR;
  const ushort* A2 = A2b + (size_t)rowBase*BSTR;
  const ushort* Bb = Bb0 + (size_t)colBase*BSTR;
  const ushort* a1p = A1 + (size_t)srow*BSTR + sc8*8;
  const ushort* a2p = A2 + (size_t)srow*BSTR + sc8*8;
  const ushort* bpt = Bb + (size_t)srow*BSTR + sc8*8;
  for (int k0 = 0; k0 < 256; k0 += 64){
    *(ushort8*)(&As1[srow*72 + sc8*8])      = *(const ushort8*)(a1p + k0);
    *(ushort8*)(&As1[(srow+32)*72 + sc8*8]) = *(const ushort8*)(a1p + (size_t)32*BSTR + k0);
    *(ushort8*)(&As2[srow*72 + sc8*8])      = *(const ushort8*)(a2p + k0);
    *(ushort8*)(&As2[(srow+32)*72 + sc8*8]) = *(const ushort8*)(a2p + (size_t)32*BSTR + k0);
    *(ushort8*)(&Bs[srow*72 + sc8*8])       = *(const ushort8*)(bpt + k0);
    *(ushort8*)(&Bs[(srow+32)*72 + sc8*8])  = *(const ushort8*)(bpt + (size_t)32*BSTR + k0);
    __syncthreads();
    MM_MFMA_PAIR(0);
    MM_MFMA_PAIR(32);
    __syncthreads();
  }
  {  // tail k=256..287 (zero pad beyond 258)
    int row4 = tid >> 2, c84 = tid & 3;
    *(ushort8*)(&As1[row4*72 + c84*8]) = *(const ushort8*)(A1 + (size_t)row4*BSTR + 256 + c84*8);
    *(ushort8*)(&As2[row4*72 + c84*8]) = *(const ushort8*)(A2 + (size_t)row4*BSTR + 256 + c84*8);
    *(ushort8*)(&Bs[row4*72 + c84*8])  = *(const ushort8*)(Bb + (size_t)row4*BSTR + 256 + c84*8);
    __syncthreads();
    MM_MFMA_PAIR(0);
  }
  auto store = [&](float* Cb, f32x4 v, int r0, int c0){
    if (c0 < HP){
      #pragma unroll
      for (int r=0;r<4;r++){
        int rr = r0 + r;
        if (rr < HP) Cb[(size_t)rr*HP + c0] = v[r];
      }
    }
  };
  store(C1b, p00, rowBase + wr +      lq*4, colBase + wc +      l15);
  store(C1b, p01, rowBase + wr +      lq*4, colBase + wc + 16 + l15);
  store(C1b, p10, rowBase + wr + 16 + lq*4, colBase + wc +      l15);
  store(C1b, p11, rowBase + wr + 16 + lq*4, colBase + wc + 16 + l15);
  store(C2b, q00, rowBase + wr +      lq*4, colBase + wc +      l15);
  store(C2b, q01, rowBase + wr +      lq*4, colBase + wc + 16 + l15);
  store(C2b, q10, rowBase + wr + 16 + lq*4, colBase + wc +      l15);
  store(C2b, q11, rowBase + wr + 16 + lq*4, colBase + wc + 16 + l15);
}

// ---- paired mm absred: opening (A1@(-B)) and dilation (A2@B), B read once --
static __device__ inline void mm_abs_pair_body(const ushort* __restrict__ A1b,
                                               const ushort* __restrict__ A2b,
                                               const ushort* __restrict__ Bb0,
                                               const float* __restrict__ Ob,
                                               double* __restrict__ slot_op,
                                               double* __restrict__ slot_dil,
                                               int bx, int by, int tid,
                                               ushort* As1, ushort* As2,
                                               ushort* BsP, ushort* BsN, double* red){
  int lane = tid & 63, wv = tid >> 6;
  int wr = (wv >> 1)*32, wc = (wv & 1)*32;
  int rowBase = bx*64, colBase = by*64;
  int l15 = lane & 15, lq = lane >> 4;
  f32x4 p00 = {0.f,0.f,0.f,0.f}, p01 = p00, p10 = p00, p11 = p00;
  f32x4 q00 = p00, q01 = p00, q10 = p00, q11 = p00;
  int srow = tid >> 3, sc8 = tid & 7;
  const ushort* A1 = A1b + (size_t)rowBase*BSTR;
  const ushort* A2 = A2b + (size_t)rowBase*BSTR;
  const ushort* Bb = Bb0 + (size_t)colBase*BSTR;
  const ushort* a1p = A1 + (size_t)srow*BSTR + sc8*8;
  const ushort* a2p = A2 + (size_t)srow*BSTR + sc8*8;
  const ushort* bpt = Bb + (size_t)srow*BSTR + sc8*8;
  ushort one = f2bf(1.0f);
  auto fixB = [&](ushort8 t8, int brow, int kbase)->ushort8{
    if (brow >= HP) return t8;                  // zero pad rows stay zero
    #pragma unroll
    for (int i=0;i<8;i++){
      int kk = kbase + i;
      if (kk < HP)
        t8[i] = (brow==0 || brow==HP-1 || kk==0 || kk==HP-1) ? one : (ushort)(t8[i] ^ 0x8000);
    }
    return t8;
  };
  for (int k0 = 0; k0 < 256; k0 += 64){
    *(ushort8*)(&As1[srow*72 + sc8*8])      = *(const ushort8*)(a1p + k0);
    *(ushort8*)(&As1[(srow+32)*72 + sc8*8]) = *(const ushort8*)(a1p + (size_t)32*BSTR + k0);
    *(ushort8*)(&As2[srow*72 + sc8*8])      = *(const ushort8*)(a2p + k0);
    *(ushort8*)(&As2[(srow+32)*72 + sc8*8]) = *(const ushort8*)(a2p + (size_t)32*BSTR + k0);
    {
      ushort8 t0 = *(const ushort8*)(bpt + k0);
      ushort8 t1 = *(const ushort8*)(bpt + (size_t)32*BSTR + k0);
      *(ushort8*)(&BsP[srow*72 + sc8*8])      = t0;
      *(ushort8*)(&BsP[(srow+32)*72 + sc8*8]) = t1;
      *(ushort8*)(&BsN[srow*72 + sc8*8])      = fixB(t0, colBase + srow,      k0 + sc8*8);
      *(ushort8*)(&BsN[(srow+32)*72 + sc8*8]) = fixB(t1, colBase + srow + 32, k0 + sc8*8);
    }
    __syncthreads();
    MM_MFMA_ABSPAIR(0);
    MM_MFMA_ABSPAIR(32);
    __syncthreads();
  }
  {
    int row4 = tid >> 2, c84 = tid & 3;
    *(ushort8*)(&As1[row4*72 + c84*8]) = *(const ushort8*)(A1 + (size_t)row4*BSTR + 256 + c84*8);
    *(ushort8*)(&As2[row4*72 + c84*8]) = *(const ushort8*)(A2 + (size_t)row4*BSTR + 256 + c84*8);
    ushort8 t0 = *(const ushort8*)(Bb + (size_t)row4*BSTR + 256 + c84*8);
    *(ushort8*)(&BsP[row4*72 + c84*8]) = t0;
    *(ushort8*)(&BsN[row4*72 + c84*8]) = fixB(t0, colBase + row4, 256 + c84*8);
    __syncthreads();
    MM_MFMA_ABSPAIR(0);
  }
  double lop = 0.0, ldl = 0.0;
  auto addq = [&](f32x4 vp, f32x4 vq, int r0, int c0){
    if (c0 < HP){
      #pragma unroll
      for (int r=0;r<4;r++){
        int rr = r0 + r;
        if (rr < HP){
          float o = Ob[(size_t)rr*HP + c0];
          float oo = (rr==0||rr==HP-1||c0==0||c0==HP-1) ? 1.0f : -o;
          lop += (double)fabsf(oo - vp[r]);
          ldl += (double)fabsf(o  - vq[r]);
        }
      }
    }
  };
  addq(p00, q00, rowBase + wr +      lq*4, colBase + wc +      l15);
  addq(p01, q01, rowBase + wr +      lq*4, colBase + wc + 16 + l15);
  addq(p10, q10, rowBase + wr + 16 + lq*4, colBase + wc +      l15);
  addq(p11, q11, rowBase + wr + 16 + lq*4, colBase + wc + 16 + l15);
  red[tid] = lop;
  __syncthreads();
  for (int s=128; s>0; s>>=1){ if (tid<s) red[tid]+=red[tid+s]; __syncthreads(); }
  if (tid==0) *slot_op = red[0];
  __syncthreads();
  red[tid] = ldl;
  __syncthreads();
  for (int s=128; s>0; s>>=1){ if (tid<s) red[tid]+=red[tid+s]; __syncthreads(); }
  if (tid==0) *slot_dil = red[0];
}

// ---- cm matvec: cm = ((colsum A)@XP - colsum x)/258 ------------------------
static __device__ inline void cm_body(int ch, const float* __restrict__ apart_,
                                      const float* __restrict__ xpart_,
                                      const float* __restrict__ XPd,
                                      float* __restrict__ cmo,
                                      float* colA, int tid){
  const float* ap = apart_ + (size_t)ch*10*320;
  for (int k = tid; k < HP; k += 256){
    float s = 0.0f;
    #pragma unroll
    for (int t=0;t<10;t++) s += ap[t*320 + k];
    colA[k] = s;
  }
  __syncthreads();
  const float* xpd = XPd + (size_t)ch*NPIX;
  const float* xp2 = xpart_ + (size_t)ch*10*320;
  for (int w = tid; w < HP; w += 256){
    float acc = 0.0f;
    for (int k=0;k<HP;k++) acc = fmaf(colA[k], xpd[(size_t)k*HP + w], acc);
    float xs = 0.0f;
    #pragma unroll
    for (int t=0;t<10;t++) xs += xp2[t*320 + w];
    cmo[ch*HP + w] = (acc - xs) * (1.0f/(float)HP);
  }
}

// ---- buildall: softmax+fc+XP+BFT+pools+col partials (unchanged) ------------
__global__ __launch_bounds__(256) void fb_buildall_k(const float* __restrict__ logits,
    float* __restrict__ XP, ushort* __restrict__ BFT,
    ushort* __restrict__ BF1, ushort* __restrict__ BF2,
    float* __restrict__ xpart, float* __restrict__ apart){
  __shared__ float s6[6][34][35];
  __shared__ float fcb[34][35];
  __shared__ ushort tbuf[32][33];
  __shared__ float cr[2][8][33];
  int tile = blockIdx.x, chunk = blockIdx.y;
  int tr = tile/10, tc = tile%10;
  int r0 = tr*32, c0 = tc*32;
  int tid = threadIdx.x;
  for (int idx = tid; idx < 34*34; idx += 256){
    int lr = idx/34, lc = idx%34;
    int h = r0 - 1 + lr, w = c0 - 1 + lc;
    float sv[6];
    if (h >= 1 && h <= 256 && w >= 1 && w <= 256){
      int oh = h-1, ow = w-1;
      float fy = 0.25f*oh - 0.375f;
      float fx = 0.25f*ow - 0.375f;
      float y0f = floorf(fy), x0f = floorf(fx);
      float ty = fy - y0f, tx2 = fx - x0f;
      int y0 = max(0, (int)y0f), y1 = min(LOGW-1, (int)y0f + 1);
      int x0 = max(0, (int)x0f), x1 = min(LOGW-1, (int)x0f + 1);
      float m = -3.402823466e+38f;
      #pragma unroll
      for (int c=0;c<6;c++){
        const float* pl = logits + c*LOGW*LOGW;
        float v00 = pl[y0*LOGW + x0], v01 = pl[y0*LOGW + x1];
        float v10 = pl[y1*LOGW + x0], v11 = pl[y1*LOGW + x1];
        float a = v00 + (v01 - v00)*tx2;
        float b = v10 + (v11 - v10)*tx2;
        float v = a + (b - a)*ty;
        sv[c] = v; m = fmaxf(m, v);
      }
      float sum = 0.0f;
      #pragma unroll
      for (int c=0;c<6;c++){ sv[c] = expf(sv[c]-m); sum += sv[c]; }
      float inv = 1.0f/sum;
      #pragma unroll
      for (int c=0;c<6;c++) sv[c] *= inv;
    } else {
      #pragma unroll
      for (int c=0;c<6;c++) sv[c] = 0.0f;
    }
    #pragma unroll
    for (int c=0;c<6;c++) s6[c][lr][lc] = sv[c];
  }
  __syncthreads();
  int tx = tid & 31, rg = tid >> 5;
  for (int cc=0; cc<CH; cc++){
    int ci = chunk*CH + cc;
    int i = ci/5, r = ci%5;
    int j = r + (r>=i ? 1 : 0);
    for (int idx = tid; idx < 34*34; idx += 256){
      int lr = idx/34, lc = idx%34;
      int h = r0 - 1 + lr, w = c0 - 1 + lc;
      float v;
      if (h < 0 || h >= HP || w < 0 || w >= HP) v = 0.0f;
      else if (h==0 || h==HP-1 || w==0 || w==HP-1) v = 1.0f;
      else v = fmaxf(0.5f*(s6[i][lr][lc] - s6[j][lr][lc]), 0.0f);
      fcb[lr][lc] = v;
    }
    __syncthreads();
    float xs_acc = 0.0f, as_acc = 0.0f;
    #pragma unroll
    for (int kk=0; kk<4; kk++){
      int lrow = rg + 8*kk;
      int h = r0 + lrow, w = c0 + tx;
      int lr = lrow + 1, lc = tx + 1;
      float xpv = fcb[lr][lc];
      ushort pmaxv, pavgv, xbfv;
      if (h >= HP || w >= HP){ pmaxv = 0; pavgv = 0; xbfv = 0; }
      else if (h==0 || h==HP-1 || w==0 || w==HP-1){
        pmaxv = f2bf(1.0f); pavgv = pmaxv; xbfv = pmaxv;
        XP[(size_t)ci*NPIX + (size_t)h*HP + w] = 1.0f;
        xs_acc += 1.0f;
        as_acc += 1.0f;
      } else {
        float mv = -3.402823466e+38f, av = 0.0f;
        #pragma unroll
        for (int dy=-1;dy<=1;dy++)
          #pragma unroll
          for (int dx=-1;dx<=1;dx++){
            float nv = fcb[lr+dy][lc+dx];
            mv = fmaxf(mv, nv); av += nv;
          }
        pmaxv = f2bf(mv);
        pavgv = f2bf(av*(1.0f/9.0f));
        xbfv  = f2bf(xpv);
        XP[(size_t)ci*NPIX + (size_t)h*HP + w] = xpv;
        xs_acc += xpv;
        as_acc += bf2f(pavgv);
      }
      size_t ob = (size_t)ci*NPB + (size_t)h*BSTR + w;
      BF1[ob] = pmaxv;
      BF2[ob] = pavgv;
      tbuf[lrow][tx] = xbfv;
    }
    cr[0][rg][tx] = xs_acc;
    cr[1][rg][tx] = as_acc;
    __syncthreads();
    if (tid < 32){
      float xs = 0.0f, as = 0.0f;
      #pragma unroll
      for (int g=0; g<8; g++){ xs += cr[0][g][tid]; as += cr[1][g][tid]; }
      xpart[((size_t)ci*10 + tr)*320 + c0 + tid] = xs;
      apart[((size_t)ci*10 + tr)*320 + c0 + tid] = as;
    }
    #pragma unroll
    for (int kk=0; kk<4; kk++){
      int a = rg + 8*kk;
      BFT[(size_t)ci*NPB + (size_t)(c0+a)*BSTR + (r0 + tx)] = tbuf[tx][a];
    }
    __syncthreads();
  }
}

// ---- paired mm store + cm: 1D grid 780, XCD-swizzled -----------------------
__global__ __launch_bounds__(256) void fb_mm_k(const ushort* __restrict__ Aop,
    const ushort* __restrict__ Adil, const ushort* __restrict__ BT,
    float* __restrict__ Cop, float* __restrict__ Cdil,
    const float* __restrict__ XPd, const float* __restrict__ apart_,
    const float* __restrict__ xpart_, float* __restrict__ cmo){
  __shared__ ushort As1[64*72];
  __shared__ ushort As2[64*72];
  __shared__ ushort Bs[64*72];
  int wg = xcd_swz(blockIdx.x, 780);
  if (wg >= 750){
    cm_body(wg - 750, apart_, xpart_, XPd, cmo, (float*)As1, threadIdx.x);
    return;
  }
  int bx = wg % 5, by = (wg/5) % 5, ch = wg/25;
  mm_pair_body(Aop + (size_t)ch*NPB, Adil + (size_t)ch*NPB, BT + (size_t)ch*NPB,
               Cop + (size_t)ch*NPIX, Cdil + (size_t)ch*NPIX,
               bx, by, threadIdx.x, As1, As2, Bs);
}

// ---- tile-fused poolrect (unchanged) ---------------------------------------
__global__ __launch_bounds__(256) void fb_poolrect_k(const float* __restrict__ F1,
    ushort* __restrict__ BF0, const float* __restrict__ XP,
    const float* __restrict__ F2, const float* __restrict__ cm,
    float* __restrict__ X1, ushort* __restrict__ BF2,
    float* __restrict__ x1part, float* __restrict__ a2part){
  __shared__ float rect[34][35];
  __shared__ float cr2[2][8][33];
  int ci = blockIdx.y;
  int tl = blockIdx.x;
  int tcx = tl/10, tty = tl%10;
  int c0 = tcx*32, r0 = tty*32;
  int tid = threadIdx.x;
  int tx = tid & 31, rg = tid >> 5;
  {
    const float* fb = F1 + (size_t)ci*NPIX;
    for (int idx = tid; idx < 34*34; idx += 256){
      int lr = idx/34, lc = idx%34;
      int h = r0 - 1 + lr, w = c0 - 1 + lc;
      rect[lr][lc] = (h >= 0 && h < HP && w >= 0 && w < HP) ? fb[(size_t)h*HP + w] : 0.0f;
    }
    __syncthreads();
    #pragma unroll
    for (int kk=0; kk<4; kk++){
      int lrow = rg + 8*kk;
      int h = r0 + lrow, w = c0 + tx;
      ushort o;
      if (h >= HP || w >= HP) o = 0;
      else if (h==0 || h==HP-1 || w==0 || w==HP-1) o = f2bf(1.0f);
      else {
        float mv = fmaxf(fmaxf(rect[lrow][tx],   rect[lrow][tx+1]),   rect[lrow][tx+2]);
        mv = fmaxf(mv, fmaxf(fmaxf(rect[lrow+1][tx], rect[lrow+1][tx+1]), rect[lrow+1][tx+2]));
        mv = fmaxf(mv, fmaxf(fmaxf(rect[lrow+2][tx], rect[lrow+2][tx+1]), rect[lrow+2][tx+2]));
        o = f2bf(mv);
      }
      BF0[(size_t)ci*NPB + (size_t)h*BSTR + w] = o;
    }
    __syncthreads();
  }
  const float* xb = XP + (size_t)ci*NPIX;
  const float* yb = F2 + (size_t)ci*NPIX;
  for (int idx = tid; idx < 34*34; idx += 256){
    int lr = idx/34, lc = idx%34;
    int h = r0 - 1 + lr, w = c0 - 1 + lc;
    float v = 0.0f;
    if (h >= 0 && h < HP && w >= 0 && w < HP){
      float xv = xb[(size_t)h*HP + w];
      float off = yb[(size_t)h*HP + w] - xv - cm[ci*HP + w];
      v = xv + fmaxf(off, 0.0f);
    }
    rect[lr][lc] = v;
  }
  __syncthreads();
  float xs_acc = 0.0f, as_acc = 0.0f;
  #pragma unroll
  for (int kk=0; kk<4; kk++){
    int lrow = rg + 8*kk;
    int h = r0 + lrow, w = c0 + tx;
    bool vpix = (h < HP && w < HP);
    ushort o;
    if (!vpix) o = 0;
    else {
      float xv = rect[lrow+1][tx+1];
      X1[(size_t)ci*NPIX + (size_t)h*HP + w] = xv;
      xs_acc += xv;
      if (h==0 || h==HP-1 || w==0 || w==HP-1){
        o = f2bf(1.0f);
        as_acc += 1.0f;
      } else {
        float av = (rect[lrow][tx]   + rect[lrow][tx+1]   + rect[lrow][tx+2])
                 + (rect[lrow+1][tx] + rect[lrow+1][tx+1] + rect[lrow+1][tx+2])
                 + (rect[lrow+2][tx] + rect[lrow+2][tx+1] + rect[lrow+2][tx+2]);
        o = f2bf(av*(1.0f/9.0f));
        as_acc += bf2f(o);
      }
    }
    BF2[(size_t)ci*NPB + (size_t)h*BSTR + w] = o;
  }
  cr2[0][rg][tx] = xs_acc;
  cr2[1][rg][tx] = as_acc;
  __syncthreads();
  if (tid < 32){
    float xs = 0.0f, as = 0.0f;
    #pragma unroll
    for (int g=0; g<8; g++){ xs += cr2[0][g][tid]; as += cr2[1][g][tid]; }
    x1part[((size_t)ci*10 + tty)*320 + c0 + tid] = xs;
    a2part[((size_t)ci*10 + tty)*320 + c0 + tid] = as;
  }
}

// ---- invrect (unchanged) ---------------------------------------------------
__global__ __launch_bounds__(256) void fb_invrect_k(const float* __restrict__ F1,
    ushort* __restrict__ An, const float* __restrict__ X1,
    const float* __restrict__ F2, const float* __restrict__ cm,
    ushort* __restrict__ An2){
  bool second = (blockIdx.x >= PBLK);
  int p = (second ? blockIdx.x - PBLK : (int)blockIdx.x)*256 + threadIdx.x;
  if (p >= PTOT) return;
  int h = p / BSTR, w = p % BSTR;
  ushort* dst = second ? An2 : An;
  if (h >= HP || w >= HP){
    #pragma unroll
    for (int c=0;c<C30;c++) dst[(size_t)c*NPB+p] = 0;
    return;
  }
  int pd = h*HP + w;
  float v[C30];
  float ss = 0.0f;
  if (!second){
    #pragma unroll
    for (int c=0;c<C30;c++){ v[c] = F1[(size_t)c*NPIX+pd]; ss = fmaf(v[c],v[c],ss); }
  } else {
    #pragma unroll
    for (int c=0;c<C30;c++){
      float xv = X1[(size_t)c*NPIX + pd];
      float off = F2[(size_t)c*NPIX + pd] - xv - cm[c*HP + w];
      float vv = xv + fmaxf(off, 0.0f);
      v[c] = vv;
      ss = fmaf(vv, vv, ss);
    }
  }
  float n = sqrtf(2.0f*ss);
  float inv = 1.0f / fmaxf(n, 1e-12f);
  #pragma unroll
  for (int c=0;c<C30;c++) dst[(size_t)c*NPB+p] = f2bf(v[c]*inv);
}

// ---- paired mm absred: 1D grid 750, XCD-swizzled ---------------------------
__global__ __launch_bounds__(256) void fb_mmabs_k(const ushort* __restrict__ Aop,
    const ushort* __restrict__ Adil, const ushort* __restrict__ BT,
    const float* __restrict__ XPop, double* __restrict__ part){
  __shared__ ushort As1[64*72];
  __shared__ ushort As2[64*72];
  __shared__ ushort BsP[64*72];
  __shared__ ushort BsN[64*72];
  __shared__ double red[256];
  int wg = xcd_swz(blockIdx.x, 750);
  int bx = wg % 5, by = (wg/5) % 5, ch = wg/25;
  int lin = by*5 + bx;
  mm_abs_pair_body(Aop + (size_t)ch*NPB, Adil + (size_t)ch*NPB, BT + (size_t)ch*NPB,
                   XPop + (size_t)ch*NPIX,
                   &part[(size_t)ch*25 + lin],
                   &part[(size_t)(C30+ch)*25 + lin],
                   bx, by, threadIdx.x, As1, As2, BsP, BsN, red);
}

__global__ void fb_finalize_k(const double* __restrict__ part,
                              const float* __restrict__ base, float* __restrict__ out){
  __shared__ double s0[256], s1[256];
  int tid = threadIdx.x;
  double l0=0.0, l1=0.0;
  for (int i=tid;i<750;i+=256){ l0 += part[i]; l1 += part[750+i]; }
  s0[tid]=l0; s1[tid]=l1; __syncthreads();
  for (int s=128;s>0;s>>=1){ if (tid<s){ s0[tid]+=s0[tid+s]; s1[tid]+=s1[tid+s]; } __syncthreads(); }
  if (tid==0) out[0] = (float)(fabs(2.0*(s0[0]-s1[0])) + (double)base[0]);
}

extern "C" void kernel_launch(void* const* d_in, const int* in_sizes, int n_in,
                              void* d_out, int out_size, void* d_ws, size_t ws_size,
                              hipStream_t stream){
  const float* logits = (const float*)d_in[0];
  const float* base   = (const float*)d_in[1];
  float* out = (float*)d_out;

  char* ws = (char*)d_ws;
  size_t off = 0;
  auto alloc = [&](size_t bytes)->char*{
    char* p = ws + off; off = (off + bytes + 255) & ~(size_t)255; return p;
  };
  double* part    = (double*)alloc(1500*sizeof(double));
  float*  cm      = (float*) alloc((size_t)C30*HP*sizeof(float));
  float*  xpart   = (float*) alloc((size_t)C30*10*320*sizeof(float));
  float*  apart   = (float*) alloc((size_t)C30*10*320*sizeof(float));
  float*  x1part  = (float*) alloc((size_t)C30*10*320*sizeof(float));
  float*  a2part  = (float*) alloc((size_t)C30*10*320*sizeof(float));
  float*  XP      = (float*) alloc((size_t)TOT*sizeof(float));
  ushort* BF0     = (ushort*)alloc((size_t)C30*NPB*sizeof(ushort));
  ushort* BFT     = (ushort*)alloc((size_t)C30*NPB*sizeof(ushort));
  ushort* BF1     = (ushort*)alloc((size_t)C30*NPB*sizeof(ushort));
  ushort* BF2     = (ushort*)alloc((size_t)C30*NPB*sizeof(ushort));
  float*  F1      = (float*) alloc((size_t)TOT*sizeof(float));
  float*  F2      = (float*) alloc((size_t)TOT*sizeof(float));
  float*  X1      = (float*) alloc((size_t)TOT*sizeof(float));
  (void)ws_size; (void)in_sizes; (void)n_in; (void)out_size;

  dim3 baGrid(100, 10);
  dim3 prGrid(100, C30);

  fb_buildall_k<<<baGrid,256,0,stream>>>(logits, XP, BFT, BF1, BF2, xpart, apart);
  fb_mm_k<<<780,256,0,stream>>>(BF1, BF2, BFT, F1, F2, XP, apart, xpart, cm);
  fb_poolrect_k<<<prGrid,256,0,stream>>>(F1, BF0, XP, F2, cm, X1, BF2, x1part, a2part);
  fb_mm_k<<<780,256,0,stream>>>(BF0, BF2, BFT, F1, F2, XP, a2part, x1part, cm);
  fb_invrect_k<<<820,256,0,stream>>>(F1, BF1, X1, F2, cm, BF0);
  fb_mmabs_k<<<750,256,0,stream>>>(BF1, BF0, BFT, XP, part);
  fb_finalize_k<<<1,256,0,stream>>>(part, base, out);
}